// Round 18
// baseline (167.795 us; speedup 1.0000x reference)
//
#include <hip/hip_runtime.h>
#include <hip/hip_bf16.h>
#include <hip/hip_cooperative_groups.h>

// SparseGCM: 2-layer causal-window GCN on MI355X — split-bf16, fragment-
// contiguous layout, SINGLE cooperative mega-kernel (3 phases + grid syncs):
//   phase1 prep (A1F + W frags) | sync | phase2 gemm1 (LDS-A + winsum
//   epilogue -> A2F) | sync | phase3 gemm2 -> out.
// Falls back to the identical 3-kernel chain if cooperative launch fails.
//
// Edges are j->i for j in [i-16,i) per batch, weights normalize to 1.0 ->
// "gather+segment_sum" == 16-wide sliding-window sum. Only outputs i in
// [512,640) matter: layer1 computes i in [496,640).
//
// Precision (R2/R4): single-bf16 fails (correlated L1 errors x16-amplified by
// the L2 window sum). Split v = hi+lo bf16; compute Ahi*Whi + Ahi*Wlo +
// Alo*Whi (3 MFMAs) ~= fp32. Validated R5-R17 (absmax 0.0039).
//
// Perf history: R5 61.2; R7 55.8; R8 49.7; R9 ABORT; R10 47.8; R11 45.5;
// R12 41.2; R14 37.4 (gemm1 LDS-A); R15 35.8 (gemm2 LDS-A); R16 35.9 and
// R17 36.1 (depth/barrier tweaks neutral -> step-floor). Sum-of-parts ~19us
// vs 35.8 measured -> ~12-16us is kernel-boundary drain/dispatch. R18: one
// cooperative kernel, 512 blocks (2/CU co-resident), phases = verbatim R15
// bodies, cg grid sync between. Unit->block maps preserve XCD colocation.

namespace cg = cooperative_groups;

namespace {

constexpr int BQ    = 64;
constexpr int FEATC = 256;
constexpr int M1 = 144;   // layer-1 rows/batch: i in [496,640)
constexpr int M2 = 128;   // layer-2 rows/batch: i in [512,640)

using ushort = unsigned short;
using short8 = __attribute__((ext_vector_type(8))) short;   // 8 bf16
using f32x4  = __attribute__((ext_vector_type(4))) float;

__device__ __forceinline__ ushort f2bf(float f) {  // RNE
  union { float f; unsigned u; } v{f};
  unsigned r = v.u + 0x7FFFu + ((v.u >> 16) & 1u);
  return (ushort)(r >> 16);
}
__device__ __forceinline__ float bf2f(ushort h) {
  union { unsigned u; float f; } v{(unsigned)h << 16};
  return v.f;
}
__device__ __forceinline__ void split2(float v, ushort& hi, ushort& lo) {
  hi = f2bf(v);
  lo = f2bf(v - bf2f(hi));
}
// tanh(x) = 1 - 2/(1 + exp2(2*log2e*x)); exp2/rcp handle the limits.
__device__ __forceinline__ float tanh_fast(float x) {
  const float e = __builtin_amdgcn_exp2f(x * 2.8853900817779268f);
  return 1.0f - 2.0f * __builtin_amdgcn_rcpf(1.0f + e);
}
__device__ __forceinline__ void gl_lds16(const ushort* g, ushort* l) {
  __builtin_amdgcn_global_load_lds(
      (const __attribute__((address_space(1))) void*)g,
      (__attribute__((address_space(3))) void*)l, 16, 0, 0);
}

// Fragment-contiguous layout. Row r, packed k in [0,512) ([self|win] for A,
// [Wself|Wnbr] for W), s = hi(0)/lo(1) (for W: W1/W2). A wave's MFMA fragment
// = contiguous 1KB block at ((rg*16 + kb)*2 + s)*512, lane-linear inside.
__device__ __forceinline__ size_t frag_idx(int row, int k, int s) {
  return ((size_t)(((row >> 4) * 16 + (k >> 5)) * 2 + s)) * 512
       + ((k >> 3) & 3) * 128 + (row & 15) * 8 + (k & 7);
}
// Same, local to one 16-row group (16384-elem block).
__device__ __forceinline__ int lofs(int row_l, int k, int s) {
  return ((k >> 5) * 2 + s) * 512 + ((k >> 3) & 3) * 128 + row_l * 8 + (k & 7);
}

// ---------------------------------------------------------------------------
// prep unit u: [0,576) = prep1 group G=4*(u%144)+u/144 (XCD-colocated);
//              [576,640) = weight transpose+split. (R10-frozen numerics)
// ---------------------------------------------------------------------------
__device__ __forceinline__ void prep_unit(
    int u, int tid, unsigned char* smem,
    const float* __restrict__ x, const float* __restrict__ nodes,
    const float* __restrict__ W1s, const float* __restrict__ W1n,
    const float* __restrict__ W2s, const float* __restrict__ W2n,
    ushort* __restrict__ A1F, ushort* __restrict__ WF1,
    ushort* __restrict__ WF2) {
  ushort* lds_o = (ushort*)smem;               // 32 KB
  float (*tile)[65] = (float(*)[65])smem;      // 16.6 KB (wprep path)
  if (u < 576) {
    const int G = 4 * (u % 144) + (u / 144);   // XCD spread permutation
    const int b = G / 9, c = G % 9, f = tid;
    const int t0 = c * 16, i0 = 496 + t0;
    const float* nb = nodes + ((size_t)b * 640) * FEATC + f;
    const float* xb = x     + ((size_t)b * 128) * FEATC + f;

    float v[32];
    #pragma unroll
    for (int d = 0; d < 32; ++d) {
      const int i = i0 - 16 + d;
      v[d] = (i < 512) ? nb[(size_t)i * FEATC] : xb[(size_t)(i - 512) * FEATC];
    }
    float win = 0.f;
    #pragma unroll
    for (int d = 0; d < 16; ++d) win += v[d];

    #pragma unroll
    for (int tt = 0; tt < 16; ++tt) {
      ushort hi, lo;
      split2(v[16 + tt], hi, lo);
      lds_o[lofs(tt, f, 0)] = hi;
      lds_o[lofs(tt, f, 1)] = lo;
      split2(win, hi, lo);
      lds_o[lofs(tt, 256 + f, 0)] = hi;
      lds_o[lofs(tt, 256 + f, 1)] = lo;
      win += v[16 + tt] - v[tt];
    }
    __syncthreads();
    ushort* dst = A1F + (size_t)G * 16384;
    #pragma unroll
    for (int it = 0; it < 8; ++it) {
      const int idx = it * 256 + tid;
      *(short8*)(dst + idx * 8) = *(const short8*)(lds_o + idx * 8);
    }
  } else {
    const int w = u - 576;
    const int z = w >> 4, rem = w & 15;
    const int k0 = (rem >> 2) * 64, n0 = (rem & 3) * 64;
    const float* src = (z == 0) ? W1s : (z == 1) ? W1n : (z == 2) ? W2s : W2n;
    ushort* dst = (z < 2) ? WF1 : WF2;
    const int koff = (z & 1) * 256;
    const int c = tid & 63, r4 = tid >> 6;
    #pragma unroll
    for (int p = 0; p < 16; ++p) {
      const int k = r4 + p * 4;
      tile[k][c] = src[(size_t)(k0 + k) * FEATC + n0 + c];
    }
    __syncthreads();
    #pragma unroll
    for (int p = 0; p < 16; ++p) {
      const int n = r4 + p * 4;
      ushort hi, lo;
      split2(tile[c][n], hi, lo);
      dst[frag_idx(n0 + n, koff + k0 + c, 0)] = hi;   // W1 (hi) slot
      dst[frag_idx(n0 + n, koff + k0 + c, 1)] = lo;   // W2 (lo) slot
    }
  }
}

// ---------------------------------------------------------------------------
// asm helpers. Rules: only asm vmem / gl_lds builtin inside pipelined
// regions; counted vmcnt via asm; raw barrier via builtin (no drain).
// ---------------------------------------------------------------------------
#define GLOAD(dst, ptr)                                                      \
  asm volatile("global_load_dwordx4 %0, %1, off"                             \
               : "=v"(dst) : "v"(ptr) : "memory")

#define WAITV(n) do {                                                        \
  asm volatile("s_waitcnt vmcnt(" #n ")" ::: "memory");                      \
  __builtin_amdgcn_sched_barrier(0);                                         \
} while (0)

#define MF(a, b, c) c = __builtin_amdgcn_mfma_f32_16x16x32_bf16(a, b, c, 0, 0, 0)

// ---------------------------------------------------------------------------
// gemm1 body (R15-validated): 80-row h1 window (16-row halo), A staged in
// LDS once per block, triple-buffered depth-2; W per-wave asm rotation.
// Winsum epilogue emits A2F fragment groups (LDS reused).
// ---------------------------------------------------------------------------
#define STAGEA(jn, kb) do {                                                  \
  gl_lds16(srcu0 + (kb) * 1024, sbase + (jn) * 5120 + u0 * 512);             \
  gl_lds16(srcu1 + (kb) * 1024, sbase + (jn) * 5120 + u1 * 512);             \
  if (g3) gl_lds16(srcu2 + (kb) * 1024, sbase + (jn) * 5120 + u2 * 512);     \
} while (0)

#define WAITW do { if (g3) { WAITV(5); } else { WAITV(4); } } while (0)

#define COMPJ2(j, WH, WL) do {                                               \
  const ushort* bp_ = sbase + (j) * 5120 + lane * 8;                         \
  const short8 a0h = *(const short8*)(bp_ + 0 * 512);                        \
  const short8 a0l = *(const short8*)(bp_ + 1 * 512);                        \
  const short8 a1h = *(const short8*)(bp_ + 2 * 512);                        \
  const short8 a1l = *(const short8*)(bp_ + 3 * 512);                        \
  const short8 a2h = *(const short8*)(bp_ + 4 * 512);                        \
  const short8 a2l = *(const short8*)(bp_ + 5 * 512);                        \
  const short8 a3h = *(const short8*)(bp_ + 6 * 512);                        \
  const short8 a3l = *(const short8*)(bp_ + 7 * 512);                        \
  const short8 a4h = *(const short8*)(bp_ + 8 * 512);                        \
  const short8 a4l = *(const short8*)(bp_ + 9 * 512);                        \
  __builtin_amdgcn_s_setprio(1);                                            \
  MF(a0h, WH, acc[0]); MF(a1h, WH, acc[1]); MF(a2h, WH, acc[2]);             \
  MF(a3h, WH, acc[3]); MF(a4h, WH, acc[4]);                                  \
  MF(a0h, WL, acc[0]); MF(a1h, WL, acc[1]); MF(a2h, WL, acc[2]);             \
  MF(a3h, WL, acc[3]); MF(a4h, WL, acc[4]);                                  \
  MF(a0l, WH, acc[0]); MF(a1l, WH, acc[1]); MF(a2l, WH, acc[2]);             \
  MF(a3l, WH, acc[3]); MF(a4l, WH, acc[4]);                                  \
  __builtin_amdgcn_s_setprio(0);                                            \
  __builtin_amdgcn_sched_barrier(0);                                        \
} while (0)

__device__ __forceinline__ void gemm1_body(
    int mx2, int ny, int tid, unsigned char* ldsmem,
    const ushort* __restrict__ A, const ushort* __restrict__ W,
    const float* __restrict__ bias, ushort* __restrict__ A2F) {
  // LDS union: [0,30720) = 3 stage bufs (10KB each) during main loop;
  // epilogue: hvt 80x68 f32 at 0 (21760B), outb at 21760 (32768B).
  ushort* sbase = (ushort*)ldsmem;
  float (*hvt)[68] = (float(*)[68])ldsmem;
  ushort* outb = (ushort*)(ldsmem + 21760);

  const int wave = tid >> 6, lane = tid & 63;
  const int lr = lane & 15, kg = lane >> 4;
  const int b = mx2 >> 1, half = mx2 & 1;
  const int rgA0 = 9 * b + 4 * half;          // first of 5 A row-groups
  const int n0 = ny * 64;
  const int ngw = ny * 4 + wave;              // W col-group for this wave

  const bool g3 = (wave < 2);
  const int uw = g3 ? wave * 3 : 6 + (wave - 2) * 2;
  const int u0 = uw, u1 = uw + 1, u2 = g3 ? uw + 2 : uw + 1;
  auto srcA = [&](int u) {
    return A + ((size_t)(rgA0 + (u >> 1)) * 32 + (u & 1)) * 512 + lane * 8;
  };
  const ushort* srcu0 = srcA(u0);
  const ushort* srcu1 = srcA(u1);
  const ushort* srcu2 = srcA(u2);

  const ushort* bW = W + (size_t)ngw * 16384 + lane * 8;

  f32x4 acc[5] = {};
  short8 w0h, w0l, w1h, w1l, w2h, w2l;

  STAGEA(0, 0); GLOAD(w0h, bW);        GLOAD(w0l, bW + 512);
  STAGEA(1, 1); GLOAD(w1h, bW + 1024); GLOAD(w1l, bW + 1536);

#define STEP(k, j, jn, WH, WL, NWH, NWL)                                     \
  WAITW; __builtin_amdgcn_s_barrier();                                       \
  COMPJ2(j, WH, WL);                                                         \
  STAGEA(jn, (k) + 2);                                                       \
  GLOAD(NWH, bW + ((k) + 2) * 1024); GLOAD(NWL, bW + ((k) + 2) * 1024 + 512)

  STEP(0, 0, 2, w0h, w0l, w2h, w2l);
  STEP(1, 1, 0, w1h, w1l, w0h, w0l);
  STEP(2, 2, 1, w2h, w2l, w1h, w1l);
  STEP(3, 0, 2, w0h, w0l, w2h, w2l);
  STEP(4, 1, 0, w1h, w1l, w0h, w0l);
  STEP(5, 2, 1, w2h, w2l, w1h, w1l);
  STEP(6, 0, 2, w0h, w0l, w2h, w2l);
  STEP(7, 1, 0, w1h, w1l, w0h, w0l);
  STEP(8, 2, 1, w2h, w2l, w1h, w1l);
  STEP(9, 0, 2, w0h, w0l, w2h, w2l);
  STEP(10, 1, 0, w1h, w1l, w0h, w0l);
  STEP(11, 2, 1, w2h, w2l, w1h, w1l);
  STEP(12, 0, 2, w0h, w0l, w2h, w2l);
  STEP(13, 1, 0, w1h, w1l, w0h, w0l);
  WAITW; __builtin_amdgcn_s_barrier();
  COMPJ2(2, w2h, w2l);
  WAITV(0); __builtin_amdgcn_s_barrier();
  COMPJ2(0, w0h, w0l);
#undef STEP

  __syncthreads();   // LDS reuse boundary (stage bufs -> hvt/outb)

  // epilogue 1: tanh -> LDS f32 tile [80 rows][64 cols]
  const float bv = bias[n0 + wave * 16 + lr];
  #pragma unroll
  for (int fr = 0; fr < 5; ++fr)
    #pragma unroll
    for (int r = 0; r < 4; ++r)
      hvt[fr * 16 + kg * 4 + r][wave * 16 + lr] = tanh_fast(acc[fr][r] + bv);
  __syncthreads();

  // epilogue 2: per-column 16-window sums + split -> outb units
  {
    const int col = tid & 63, q = tid >> 6;
    float hv[32];
    #pragma unroll
    for (int d = 0; d < 32; ++d) hv[d] = hvt[q * 16 + d][col];
    float win = 0.f;
    #pragma unroll
    for (int d = 0; d < 16; ++d) win += hv[d];

    const int su = ((q * 4 + (col >> 5)) * 2) * 512
                 + ((col >> 3) & 3) * 128 + (col & 7);
    const int wu = ((q * 4 + 2 + (col >> 5)) * 2) * 512
                 + ((col >> 3) & 3) * 128 + (col & 7);
    #pragma unroll
    for (int tt = 0; tt < 16; ++tt) {
      ushort hi, lo;
      split2(hv[16 + tt], hi, lo);
      outb[su + tt * 8]       = hi;
      outb[su + tt * 8 + 512] = lo;
      split2(win, hi, lo);
      outb[wu + tt * 8]       = hi;
      outb[wu + tt * 8 + 512] = lo;
      win += hv[16 + tt] - hv[tt];
    }
  }
  __syncthreads();

  // epilogue 3: burst copy 32 units of 1KB to A2F
  const int rg20 = 4 * mx2;
  #pragma unroll
  for (int it = 0; it < 8; ++it) {
    const int lin = it * 2048 + tid * 8;
    const int u = lin >> 9, w = lin & 511;
    const int uq = u >> 3, ukbl = (u >> 1) & 3, us = u & 1;
    const int KB = (ukbl < 2) ? (2 * ny + ukbl) : (8 + 2 * ny + (ukbl - 2));
    const size_t dst = ((size_t)((rg20 + uq) * 16 + KB) * 2 + us) * 512 + w;
    *(short8*)(A2F + dst) = *(const short8*)(outb + lin);
  }
}

// ---------------------------------------------------------------------------
// gemm2 body (R15-validated): mirror LDS-A structure, no halo. Depth-2,
// 3 bufs (24KB). Wave = 16-col W strip x 64 rows (4 row-frags, 12 MFMA/step).
// ---------------------------------------------------------------------------
#define STAGE2(jn, kb) do {                                                  \
  gl_lds16(srcv0 + (kb) * 1024, sb2 + (jn) * 4096 + v0 * 512);               \
  gl_lds16(srcv1 + (kb) * 1024, sb2 + (jn) * 4096 + v1 * 512);               \
} while (0)

#define COMPK(j, WH, WL) do {                                                \
  const ushort* bp_ = sb2 + (j) * 4096 + lane * 8;                           \
  const short8 a0h = *(const short8*)(bp_ + 0 * 512);                        \
  const short8 a0l = *(const short8*)(bp_ + 1 * 512);                        \
  const short8 a1h = *(const short8*)(bp_ + 2 * 512);                        \
  const short8 a1l = *(const short8*)(bp_ + 3 * 512);                        \
  const short8 a2h = *(const short8*)(bp_ + 4 * 512);                        \
  const short8 a2l = *(const short8*)(bp_ + 5 * 512);                        \
  const short8 a3h = *(const short8*)(bp_ + 6 * 512);                        \
  const short8 a3l = *(const short8*)(bp_ + 7 * 512);                        \
  __builtin_amdgcn_s_setprio(1);                                            \
  MF(a0h, WH, acc[0]); MF(a1h, WH, acc[1]);                                  \
  MF(a2h, WH, acc[2]); MF(a3h, WH, acc[3]);                                  \
  MF(a0h, WL, acc[0]); MF(a1h, WL, acc[1]);                                  \
  MF(a2h, WL, acc[2]); MF(a3h, WL, acc[3]);                                  \
  MF(a0l, WH, acc[0]); MF(a1l, WH, acc[1]);                                  \
  MF(a2l, WH, acc[2]); MF(a3l, WH, acc[3]);                                  \
  __builtin_amdgcn_s_setprio(0);                                            \
  __builtin_amdgcn_sched_barrier(0);                                        \
} while (0)

__device__ __forceinline__ void gemm2_body(
    int mx, int ny2, int tid, unsigned char* lds2,
    const ushort* __restrict__ A, const ushort* __restrict__ W,
    const float* __restrict__ bias, float* __restrict__ out) {
  ushort* sb2 = (ushort*)lds2;   // 3 x 8KB stage bufs

  const int wave = tid >> 6, lane = tid & 63;
  const int lr = lane & 15, kg = lane >> 4;
  const int rg0 = mx * 4;                     // 4 A row-groups (64 rows)
  const int ngw = ny2 * 4 + wave;             // W col-group for this wave
  const int n0col = ngw * 16;

  const int v0 = wave * 2, v1 = wave * 2 + 1; // A staging units
  auto srcA = [&](int u) {
    return A + ((size_t)(rg0 + (u >> 1)) * 32 + (u & 1)) * 512 + lane * 8;
  };
  const ushort* srcv0 = srcA(v0);
  const ushort* srcv1 = srcA(v1);
  const ushort* bW = W + (size_t)ngw * 16384 + lane * 8;

  f32x4 acc[4] = {};
  short8 w0h, w0l, w1h, w1l, w2h, w2l;

  STAGE2(0, 0); GLOAD(w0h, bW);        GLOAD(w0l, bW + 512);
  STAGE2(1, 1); GLOAD(w1h, bW + 1024); GLOAD(w1l, bW + 1536);

#define STEP2(k, j, jn, WH, WL, NWH, NWL)                                    \
  WAITV(4); __builtin_amdgcn_s_barrier();                                    \
  COMPK(j, WH, WL);                                                          \
  STAGE2(jn, (k) + 2);                                                       \
  GLOAD(NWH, bW + ((k) + 2) * 1024); GLOAD(NWL, bW + ((k) + 2) * 1024 + 512)

  STEP2(0, 0, 2, w0h, w0l, w2h, w2l);
  STEP2(1, 1, 0, w1h, w1l, w0h, w0l);
  STEP2(2, 2, 1, w2h, w2l, w1h, w1l);
  STEP2(3, 0, 2, w0h, w0l, w2h, w2l);
  STEP2(4, 1, 0, w1h, w1l, w0h, w0l);
  STEP2(5, 2, 1, w2h, w2l, w1h, w1l);
  STEP2(6, 0, 2, w0h, w0l, w2h, w2l);
  STEP2(7, 1, 0, w1h, w1l, w0h, w0l);
  STEP2(8, 2, 1, w2h, w2l, w1h, w1l);
  STEP2(9, 0, 2, w0h, w0l, w2h, w2l);
  STEP2(10, 1, 0, w1h, w1l, w0h, w0l);
  STEP2(11, 2, 1, w2h, w2l, w1h, w1l);
  STEP2(12, 0, 2, w0h, w0l, w2h, w2l);
  STEP2(13, 1, 0, w1h, w1l, w0h, w0l);
  WAITV(4); __builtin_amdgcn_s_barrier();
  COMPK(2, w2h, w2l);
  WAITV(0); __builtin_amdgcn_s_barrier();
  COMPK(0, w0h, w0l);
#undef STEP2

  // epilogue: bias + fast tanh, row-major f32 out
  const float bv = bias[n0col + lr];
  #pragma unroll
  for (int fr = 0; fr < 4; ++fr)
    #pragma unroll
    for (int r = 0; r < 4; ++r) {
      const int row = mx * 64 + fr * 16 + kg * 4 + r;
      out[(size_t)row * FEATC + n0col + lr] = tanh_fast(acc[fr][r] + bv);
    }
}

// ---------------------------------------------------------------------------
// Mega cooperative kernel: 512 blocks (2/CU co-resident), 3 phases.
// ---------------------------------------------------------------------------
__global__ __launch_bounds__(256, 2) void mega_kernel(
    const float* __restrict__ x, const float* __restrict__ nodes,
    const float* __restrict__ W1s, const float* __restrict__ W1n,
    const float* __restrict__ W2s, const float* __restrict__ W2n,
    const float* __restrict__ b1, const float* __restrict__ b2,
    ushort* A1F, ushort* A2F, ushort* WF1, ushort* WF2,
    float* __restrict__ out) {
  __shared__ __align__(16) unsigned char smem[54528];
  const int blk = blockIdx.x;
  const int tid = threadIdx.x;
  cg::grid_group grid = cg::this_grid();

  // phase 1: prep (640 units over 512 blocks; blocks 0..127 take two)
  prep_unit(blk, tid, smem, x, nodes, W1s, W1n, W2s, W2n, A1F, WF1, WF2);
  if (blk < 128) {
    __syncthreads();
    prep_unit(512 + blk, tid, smem, x, nodes, W1s, W1n, W2s, W2n,
              A1F, WF1, WF2);
  }
  grid.sync();

  // phase 2: gemm1 (mx2 = blk%128 -> XCD blk%8 == colocation with phase 1/3)
  gemm1_body(blk % 128, blk / 128, tid, smem, A1F, WF1, b1, A2F);
  grid.sync();

  // phase 3: gemm2
  gemm2_body(blk % 128, blk / 128, tid, smem, A2F, WF2, b2, out);
}

// --------------- standalone fallbacks (identical bodies) -------------------
__global__ __launch_bounds__(256) void prep_kernel_sa(
    const float* __restrict__ x, const float* __restrict__ nodes,
    const float* __restrict__ W1s, const float* __restrict__ W1n,
    const float* __restrict__ W2s, const float* __restrict__ W2n,
    ushort* A1F, ushort* WF1, ushort* WF2) {
  __shared__ __align__(16) unsigned char smem[54528];
  prep_unit(blockIdx.x, threadIdx.x, smem, x, nodes, W1s, W1n, W2s, W2n,
            A1F, WF1, WF2);
}
__global__ __launch_bounds__(256, 2) void gemm1_kernel_sa(
    const ushort* __restrict__ A, const ushort* __restrict__ W,
    const float* __restrict__ bias, ushort* A2F) {
  __shared__ __align__(16) unsigned char smem[54528];
  gemm1_body(blockIdx.x, blockIdx.y, threadIdx.x, smem, A, W, bias, A2F);
}
__global__ __launch_bounds__(256, 2) void gemm2_kernel_sa(
    const ushort* __restrict__ A, const ushort* __restrict__ W,
    const float* __restrict__ bias, float* out) {
  __shared__ __align__(16) unsigned char smem[54528];
  gemm2_body(blockIdx.x, blockIdx.y, threadIdx.x, smem, A, W, bias, out);
}

}  // namespace

extern "C" void kernel_launch(void* const* d_in, const int* in_sizes, int n_in,
                              void* d_out, int out_size, void* d_ws, size_t ws_size,
                              hipStream_t stream) {
  const float* x     = (const float*)d_in[0];
  const float* nodes = (const float*)d_in[1];
  // d_in[2] = edge_weight: forward value ew/ew == 1.0 -> unused.
  const float* W1s = (const float*)d_in[3];
  const float* W1n = (const float*)d_in[4];
  const float* b1  = (const float*)d_in[5];
  const float* W2s = (const float*)d_in[6];
  const float* W2n = (const float*)d_in[7];
  const float* b2  = (const float*)d_in[8];
  float* out = (float*)d_out;

  // workspace (ushort): A1F + A2F + WF1 + WF2 = 36.7 MB
  const size_t a1_sz = (size_t)BQ * M1 * 1024;      // 9,437,184
  const size_t a2_sz = (size_t)BQ * M2 * 1024;      // 8,388,608
  const size_t wf_sz = (size_t)16 * 16 * 2 * 512;   // 262,144 per layer
  const size_t need = (a1_sz + a2_sz + 2 * wf_sz) * sizeof(ushort);
  if (ws_size < need) return;

  ushort* p = (ushort*)d_ws;
  ushort* A1F = p; p += a1_sz;
  ushort* A2F = p; p += a2_sz;
  ushort* WF1 = p; p += wf_sz;
  ushort* WF2 = p; p += wf_sz;

  void* args[] = {(void*)&x, (void*)&nodes, (void*)&W1s, (void*)&W1n,
                  (void*)&W2s, (void*)&W2n, (void*)&b1, (void*)&b2,
                  (void*)&A1F, (void*)&A2F, (void*)&WF1, (void*)&WF2,
                  (void*)&out};
  hipError_t err = hipLaunchCooperativeKernel(
      (const void*)mega_kernel, dim3(512), dim3(256), args, 0, stream);
  if (err != hipSuccess) {
    // deterministic fallback: identical 3-kernel chain
    prep_kernel_sa<<<640, 256, 0, stream>>>(x, nodes, W1s, W1n, W2s, W2n,
                                            A1F, WF1, WF2);
    gemm1_kernel_sa<<<dim3(128, 4), 256, 0, stream>>>(A1F, WF1, b1, A2F);
    gemm2_kernel_sa<<<dim3(128, 4), 256, 0, stream>>>(A2F, WF2, b2, out);
  }
}

// Round 19
// 37.766 us; speedup vs baseline: 4.4430x; 4.4430x over previous
//
#include <hip/hip_runtime.h>
#include <hip/hip_bf16.h>

// SparseGCM: 2-layer causal-window GCN on MI355X — split-bf16, fragment-
// contiguous layout, 3-kernel chain, BOTH gemms with LDS-shared A:
//   prep_fused -> gemm1_fused (LDS-A + halo winsum epilogue) -> gemm2_lds.
//
// Edges are j->i for j in [i-16,i) per batch, weights normalize to 1.0 ->
// "gather+segment_sum" == 16-wide sliding-window sum. Only outputs i in
// [512,640) matter: layer1 computes i in [496,640).
//
// Precision (R2/R4): single-bf16 fails (correlated L1 errors x16-amplified by
// the L2 window sum). Split v = hi+lo bf16; compute Ahi*Whi + Ahi*Wlo +
// Alo*Whi (3 MFMAs) ~= fp32. Validated R5-R17 (absmax 0.0039).
//
// Perf history: R5 61.2; R7 55.8; R8 49.7; R9 ABORT (compiler vmem inside
// asm-vmcnt region); R10 47.8; R11 45.5; R12 41.2; R13 41.7 (neutral);
// R14 37.4 (gemm1 LDS-A); R15 35.8 (gemm2 LDS-A); R16 35.9 / R17 36.1
// (depth/barrier tweaks neutral); R18 167.8 (cooperative grid.sync DISASTER
// — grid-wide sync costs far more than kernel-boundary drains; reverted).
// R19 = R15 + gemm2 at 4 blocks/CU: 32-row tiles, grid (256,4), launch
// bounds (256,4), 12KB LDS, uniform vmcnt(3) cohorts; XCD colocation kept
// via bijective remap bx%8 == (mx>>1)%8 == gemm1 writer XCD.

namespace {

constexpr int BQ    = 64;
constexpr int FEATC = 256;
constexpr int M1 = 144;   // layer-1 rows/batch: i in [496,640)
constexpr int M2 = 128;   // layer-2 rows/batch: i in [512,640)

using ushort = unsigned short;
using short8 = __attribute__((ext_vector_type(8))) short;   // 8 bf16
using f32x4  = __attribute__((ext_vector_type(4))) float;

__device__ __forceinline__ ushort f2bf(float f) {  // RNE
  union { float f; unsigned u; } v{f};
  unsigned r = v.u + 0x7FFFu + ((v.u >> 16) & 1u);
  return (ushort)(r >> 16);
}
__device__ __forceinline__ float bf2f(ushort h) {
  union { unsigned u; float f; } v{(unsigned)h << 16};
  return v.f;
}
__device__ __forceinline__ void split2(float v, ushort& hi, ushort& lo) {
  hi = f2bf(v);
  lo = f2bf(v - bf2f(hi));
}
// tanh(x) = 1 - 2/(1 + exp2(2*log2e*x)); exp2/rcp handle the limits.
__device__ __forceinline__ float tanh_fast(float x) {
  const float e = __builtin_amdgcn_exp2f(x * 2.8853900817779268f);
  return 1.0f - 2.0f * __builtin_amdgcn_rcpf(1.0f + e);
}
__device__ __forceinline__ void gl_lds16(const ushort* g, ushort* l) {
  __builtin_amdgcn_global_load_lds(
      (const __attribute__((address_space(1))) void*)g,
      (__attribute__((address_space(3))) void*)l, 16, 0, 0);
}

// Fragment-contiguous layout. Row r, packed k in [0,512) ([self|win] for A,
// [Wself|Wnbr] for W), s = hi(0)/lo(1) (for W: W1/W2). A wave's MFMA fragment
// = contiguous 1KB block at ((rg*16 + kb)*2 + s)*512, lane-linear inside.
__device__ __forceinline__ size_t frag_idx(int row, int k, int s) {
  return ((size_t)(((row >> 4) * 16 + (k >> 5)) * 2 + s)) * 512
       + ((k >> 3) & 3) * 128 + (row & 15) * 8 + (k & 7);
}
// Same, local to one 16-row group (16384-elem block).
__device__ __forceinline__ int lofs(int row_l, int k, int s) {
  return ((k >> 5) * 2 + s) * 512 + ((k >> 3) & 3) * 128 + row_l * 8 + (k & 7);
}

// ---------------------------------------------------------------------------
// prep_fused: blocks [0,576) = prep1 (A1F via LDS burst, XCD-permuted);
//             blocks [576,640) = weight transpose+split.  (R10-frozen)
// ---------------------------------------------------------------------------
__global__ __launch_bounds__(256) void prep_fused(
    const float* __restrict__ x, const float* __restrict__ nodes,
    const float* __restrict__ W1s, const float* __restrict__ W1n,
    const float* __restrict__ W2s, const float* __restrict__ W2n,
    ushort* __restrict__ A1F, ushort* __restrict__ WF1,
    ushort* __restrict__ WF2) {
  __shared__ ushort lds_o[16384];   // one 16-row frag group (32 KB)
  __shared__ float tile[64][65];
  const int blk = blockIdx.x;
  if (blk < 576) {
    const int G = 4 * (blk % 144) + (blk / 144);   // XCD spread permutation
    const int b = G / 9, c = G % 9, f = threadIdx.x;
    const int t0 = c * 16, i0 = 496 + t0;
    const float* nb = nodes + ((size_t)b * 640) * FEATC + f;
    const float* xb = x     + ((size_t)b * 128) * FEATC + f;

    float v[32];
    #pragma unroll
    for (int d = 0; d < 32; ++d) {
      const int i = i0 - 16 + d;
      v[d] = (i < 512) ? nb[(size_t)i * FEATC] : xb[(size_t)(i - 512) * FEATC];
    }
    float win = 0.f;
    #pragma unroll
    for (int d = 0; d < 16; ++d) win += v[d];

    #pragma unroll
    for (int tt = 0; tt < 16; ++tt) {
      ushort hi, lo;
      split2(v[16 + tt], hi, lo);
      lds_o[lofs(tt, f, 0)] = hi;
      lds_o[lofs(tt, f, 1)] = lo;
      split2(win, hi, lo);
      lds_o[lofs(tt, 256 + f, 0)] = hi;
      lds_o[lofs(tt, 256 + f, 1)] = lo;
      win += v[16 + tt] - v[tt];
    }
    __syncthreads();
    ushort* dst = A1F + (size_t)G * 16384;
    #pragma unroll
    for (int it = 0; it < 8; ++it) {
      const int idx = it * 256 + threadIdx.x;
      *(short8*)(dst + idx * 8) = *(const short8*)(lds_o + idx * 8);
    }
  } else {
    const int w = blk - 576;
    const int z = w >> 4, rem = w & 15;
    const int k0 = (rem >> 2) * 64, n0 = (rem & 3) * 64;
    const float* src = (z == 0) ? W1s : (z == 1) ? W1n : (z == 2) ? W2s : W2n;
    ushort* dst = (z < 2) ? WF1 : WF2;
    const int koff = (z & 1) * 256;
    const int c = threadIdx.x & 63, r4 = threadIdx.x >> 6;
    #pragma unroll
    for (int p = 0; p < 16; ++p) {
      const int k = r4 + p * 4;
      tile[k][c] = src[(size_t)(k0 + k) * FEATC + n0 + c];
    }
    __syncthreads();
    #pragma unroll
    for (int p = 0; p < 16; ++p) {
      const int n = r4 + p * 4;
      ushort hi, lo;
      split2(tile[c][n], hi, lo);
      dst[frag_idx(n0 + n, koff + k0 + c, 0)] = hi;   // W1 (hi) slot
      dst[frag_idx(n0 + n, koff + k0 + c, 1)] = lo;   // W2 (lo) slot
    }
  }
}

// ---------------------------------------------------------------------------
// Shared asm helpers. Rules: only asm vmem / gl_lds builtin inside pipelined
// regions; counted vmcnt via asm; raw barrier via builtin (no drain).
// ---------------------------------------------------------------------------
#define GLOAD(dst, ptr)                                                      \
  asm volatile("global_load_dwordx4 %0, %1, off"                             \
               : "=v"(dst) : "v"(ptr) : "memory")

#define WAITV(n) do {                                                        \
  asm volatile("s_waitcnt vmcnt(" #n ")" ::: "memory");                      \
  __builtin_amdgcn_sched_barrier(0);                                         \
} while (0)

#define MF(a, b, c) c = __builtin_amdgcn_mfma_f32_16x16x32_bf16(a, b, c, 0, 0, 0)

// ---------------------------------------------------------------------------
// gemm1_fused (R14/R15-validated): 80-row h1 window (16-row halo), A staged
// in LDS once per block, triple-buffered depth-2; W per-wave asm rotation.
// Winsum epilogue emits A2F fragment groups (LDS reused).
// ---------------------------------------------------------------------------
#define STAGEA(jn, kb) do {                                                  \
  gl_lds16(srcu0 + (kb) * 1024, sbase + (jn) * 5120 + u0 * 512);             \
  gl_lds16(srcu1 + (kb) * 1024, sbase + (jn) * 5120 + u1 * 512);             \
  if (g3) gl_lds16(srcu2 + (kb) * 1024, sbase + (jn) * 5120 + u2 * 512);     \
} while (0)

#define WAITW do { if (g3) { WAITV(5); } else { WAITV(4); } } while (0)

#define COMPJ2(j, WH, WL) do {                                               \
  const ushort* bp_ = sbase + (j) * 5120 + lane * 8;                         \
  const short8 a0h = *(const short8*)(bp_ + 0 * 512);                        \
  const short8 a0l = *(const short8*)(bp_ + 1 * 512);                        \
  const short8 a1h = *(const short8*)(bp_ + 2 * 512);                        \
  const short8 a1l = *(const short8*)(bp_ + 3 * 512);                        \
  const short8 a2h = *(const short8*)(bp_ + 4 * 512);                        \
  const short8 a2l = *(const short8*)(bp_ + 5 * 512);                        \
  const short8 a3h = *(const short8*)(bp_ + 6 * 512);                        \
  const short8 a3l = *(const short8*)(bp_ + 7 * 512);                        \
  const short8 a4h = *(const short8*)(bp_ + 8 * 512);                        \
  const short8 a4l = *(const short8*)(bp_ + 9 * 512);                        \
  __builtin_amdgcn_s_setprio(1);                                            \
  MF(a0h, WH, acc[0]); MF(a1h, WH, acc[1]); MF(a2h, WH, acc[2]);             \
  MF(a3h, WH, acc[3]); MF(a4h, WH, acc[4]);                                  \
  MF(a0h, WL, acc[0]); MF(a1h, WL, acc[1]); MF(a2h, WL, acc[2]);             \
  MF(a3h, WL, acc[3]); MF(a4h, WL, acc[4]);                                  \
  MF(a0l, WH, acc[0]); MF(a1l, WH, acc[1]); MF(a2l, WH, acc[2]);             \
  MF(a3l, WH, acc[3]); MF(a4l, WH, acc[4]);                                  \
  __builtin_amdgcn_s_setprio(0);                                            \
  __builtin_amdgcn_sched_barrier(0);                                        \
} while (0)

__global__ __launch_bounds__(256, 2) void gemm1_fused(
    const ushort* __restrict__ A, const ushort* __restrict__ W,
    const float* __restrict__ bias, ushort* __restrict__ A2F) {
  // LDS union: [0,30720) = 3 stage bufs (10KB each) during main loop;
  // epilogue reuses: hvt 80x68 f32 at 0 (21760B), outb at 21760 (32768B).
  __shared__ __align__(16) unsigned char ldsmem[54528];
  ushort* sbase = (ushort*)ldsmem;
  float (*hvt)[68] = (float(*)[68])ldsmem;
  ushort* outb = (ushort*)(ldsmem + 21760);

  const int tid = threadIdx.x;
  const int wave = tid >> 6, lane = tid & 63;
  const int lr = lane & 15, kg = lane >> 4;
  const int mx2 = blockIdx.x, ny = blockIdx.y;
  const int b = mx2 >> 1, half = mx2 & 1;
  const int rgA0 = 9 * b + 4 * half;          // first of 5 A row-groups
  const int n0 = ny * 64;
  const int ngw = ny * 4 + wave;              // W col-group for this wave

  // A staging unit assignment: unit u = g*2+s; waves 0,1 own {0..2},{3..5};
  // waves 2,3 own {6,7},{8,9}.
  const bool g3 = (wave < 2);
  const int uw = g3 ? wave * 3 : 6 + (wave - 2) * 2;
  const int u0 = uw, u1 = uw + 1, u2 = g3 ? uw + 2 : uw + 1;
  auto srcA = [&](int u) {
    return A + ((size_t)(rgA0 + (u >> 1)) * 32 + (u & 1)) * 512 + lane * 8;
  };
  const ushort* srcu0 = srcA(u0);
  const ushort* srcu1 = srcA(u1);
  const ushort* srcu2 = srcA(u2);

  const ushort* bW = W + (size_t)ngw * 16384 + lane * 8;

  f32x4 acc[5] = {};
  short8 w0h, w0l, w1h, w1l, w2h, w2l;

  // prologue: stage steps 0,1 (interleaved S,W so FIFO wait counts work)
  STAGEA(0, 0); GLOAD(w0h, bW);        GLOAD(w0l, bW + 512);
  STAGEA(1, 1); GLOAD(w1h, bW + 1024); GLOAD(w1l, bW + 1536);

#define STEP(k, j, jn, WH, WL, NWH, NWL)                                     \
  WAITW; __builtin_amdgcn_s_barrier();                                       \
  COMPJ2(j, WH, WL);                                                         \
  STAGEA(jn, (k) + 2);                                                       \
  GLOAD(NWH, bW + ((k) + 2) * 1024); GLOAD(NWL, bW + ((k) + 2) * 1024 + 512)

  STEP(0, 0, 2, w0h, w0l, w2h, w2l);
  STEP(1, 1, 0, w1h, w1l, w0h, w0l);
  STEP(2, 2, 1, w2h, w2l, w1h, w1l);
  STEP(3, 0, 2, w0h, w0l, w2h, w2l);
  STEP(4, 1, 0, w1h, w1l, w0h, w0l);
  STEP(5, 2, 1, w2h, w2l, w1h, w1l);
  STEP(6, 0, 2, w0h, w0l, w2h, w2l);
  STEP(7, 1, 0, w1h, w1l, w0h, w0l);
  STEP(8, 2, 1, w2h, w2l, w1h, w1l);
  STEP(9, 0, 2, w0h, w0l, w2h, w2l);
  STEP(10, 1, 0, w1h, w1l, w0h, w0l);
  STEP(11, 2, 1, w2h, w2l, w1h, w1l);
  STEP(12, 0, 2, w0h, w0l, w2h, w2l);
  STEP(13, 1, 0, w1h, w1l, w0h, w0l);
  WAITW; __builtin_amdgcn_s_barrier();
  COMPJ2(2, w2h, w2l);
  WAITV(0); __builtin_amdgcn_s_barrier();
  COMPJ2(0, w0h, w0l);
#undef STEP

  __syncthreads();   // LDS reuse boundary (stage bufs -> hvt/outb)

  // ---- epilogue 1: tanh -> LDS f32 tile [80 rows][64 cols] ----
  const float bv = bias[n0 + wave * 16 + lr];
  #pragma unroll
  for (int fr = 0; fr < 5; ++fr)
    #pragma unroll
    for (int r = 0; r < 4; ++r)
      hvt[fr * 16 + kg * 4 + r][wave * 16 + lr] = tanh_fast(acc[fr][r] + bv);
  __syncthreads();

  // ---- epilogue 2: per-column 16-window sums + split -> outb units ----
  {
    const int col = tid & 63, q = tid >> 6;
    float hv[32];
    #pragma unroll
    for (int d = 0; d < 32; ++d) hv[d] = hvt[q * 16 + d][col];
    float win = 0.f;
    #pragma unroll
    for (int d = 0; d < 16; ++d) win += hv[d];

    const int su = ((q * 4 + (col >> 5)) * 2) * 512
                 + ((col >> 3) & 3) * 128 + (col & 7);
    const int wu = ((q * 4 + 2 + (col >> 5)) * 2) * 512
                 + ((col >> 3) & 3) * 128 + (col & 7);
    #pragma unroll
    for (int tt = 0; tt < 16; ++tt) {
      ushort hi, lo;
      split2(hv[16 + tt], hi, lo);
      outb[su + tt * 8]       = hi;
      outb[su + tt * 8 + 512] = lo;
      split2(win, hi, lo);
      outb[wu + tt * 8]       = hi;
      outb[wu + tt * 8 + 512] = lo;
      win += hv[16 + tt] - hv[tt];
    }
  }
  __syncthreads();

  // ---- epilogue 3: burst copy 32 units of 1KB to A2F ----
  const int rg20 = 4 * mx2;
  #pragma unroll
  for (int it = 0; it < 8; ++it) {
    const int lin = it * 2048 + tid * 8;
    const int u = lin >> 9, w = lin & 511;
    const int uq = u >> 3, ukbl = (u >> 1) & 3, us = u & 1;
    const int KB = (ukbl < 2) ? (2 * ny + ukbl) : (8 + 2 * ny + (ukbl - 2));
    const size_t dst = ((size_t)((rg20 + uq) * 16 + KB) * 2 + us) * 512 + w;
    *(short8*)(A2F + dst) = *(const short8*)(outb + lin);
  }
}

// ---------------------------------------------------------------------------
// gemm2_lds (R19): 32-row tiles, grid (256,4), 4 blocks/CU for TLP.
// Wave = 16-col W strip x 32 rows (2 row-frags, 6 MFMA/step). A staged
// once/block: 4 units of 1KB per K-step, 1 unit/wave (uniform cohort =
// 1 gl_lds + 2 W loads -> steady vmcnt(3)). Triple-buffered (12KB), depth-2.
// XCD colocation: bx remap so bx%8 == (mx>>1)%8 == gemm1 writer XCD.
// ---------------------------------------------------------------------------
#define STG2(jn, kb) gl_lds16(srcv + (kb) * 1024, sb2 + (jn) * 2048 + v * 512)

#define CK2(j, WH, WL) do {                                                  \
  const ushort* bp_ = sb2 + (j) * 2048 + lane * 8;                           \
  const short8 a0h = *(const short8*)(bp_ + 0 * 512);                        \
  const short8 a0l = *(const short8*)(bp_ + 1 * 512);                        \
  const short8 a1h = *(const short8*)(bp_ + 2 * 512);                        \
  const short8 a1l = *(const short8*)(bp_ + 3 * 512);                        \
  __builtin_amdgcn_s_setprio(1);                                            \
  MF(a0h, WH, acc[0]); MF(a1h, WH, acc[1]);                                  \
  MF(a0h, WL, acc[0]); MF(a1h, WL, acc[1]);                                  \
  MF(a0l, WH, acc[0]); MF(a1l, WH, acc[1]);                                  \
  __builtin_amdgcn_s_setprio(0);                                            \
  __builtin_amdgcn_sched_barrier(0);                                        \
} while (0)

__global__ __launch_bounds__(256, 4) void gemm2_lds(
    const ushort* __restrict__ A, const ushort* __restrict__ W,
    const float* __restrict__ bias, float* __restrict__ out) {
  __shared__ __align__(16) ushort sb2[3 * 2048];   // 12 KB

  const int tid = threadIdx.x;
  const int wave = tid >> 6, lane = tid & 63;
  const int lr = lane & 15, kg = lane >> 4;
  const int bx = blockIdx.x, ny2 = blockIdx.y;
  // bijective remap: mx = 2r + 16*(q>>1) + (q&1) -> (mx>>1)%8 == bx%8
  const int rr = bx & 7, q = bx >> 3;
  const int mx = 2 * rr + 16 * (q >> 1) + (q & 1);   // [0,256)
  const int rg0 = mx * 2;                     // 2 A row-groups (32 rows)
  const int ngw = ny2 * 4 + wave;             // W col-group for this wave
  const int n0col = ngw * 16;

  const int v = wave;                         // this wave's staging unit
  const ushort* srcv =
      A + ((size_t)(rg0 + (v >> 1)) * 32 + (v & 1)) * 512 + lane * 8;
  const ushort* bW = W + (size_t)ngw * 16384 + lane * 8;

  f32x4 acc[2] = {};
  short8 w0h, w0l, w1h, w1l, w2h, w2l;

  STG2(0, 0); GLOAD(w0h, bW);        GLOAD(w0l, bW + 512);
  STG2(1, 1); GLOAD(w1h, bW + 1024); GLOAD(w1l, bW + 1536);

#define STEP2(k, j, jn, WH, WL, NWH, NWL)                                    \
  WAITV(3); __builtin_amdgcn_s_barrier();                                    \
  CK2(j, WH, WL);                                                            \
  STG2(jn, (k) + 2);                                                         \
  GLOAD(NWH, bW + ((k) + 2) * 1024); GLOAD(NWL, bW + ((k) + 2) * 1024 + 512)

  STEP2(0, 0, 2, w0h, w0l, w2h, w2l);
  STEP2(1, 1, 0, w1h, w1l, w0h, w0l);
  STEP2(2, 2, 1, w2h, w2l, w1h, w1l);
  STEP2(3, 0, 2, w0h, w0l, w2h, w2l);
  STEP2(4, 1, 0, w1h, w1l, w0h, w0l);
  STEP2(5, 2, 1, w2h, w2l, w1h, w1l);
  STEP2(6, 0, 2, w0h, w0l, w2h, w2l);
  STEP2(7, 1, 0, w1h, w1l, w0h, w0l);
  STEP2(8, 2, 1, w2h, w2l, w1h, w1l);
  STEP2(9, 0, 2, w0h, w0l, w2h, w2l);
  STEP2(10, 1, 0, w1h, w1l, w0h, w0l);
  STEP2(11, 2, 1, w2h, w2l, w1h, w1l);
  STEP2(12, 0, 2, w0h, w0l, w2h, w2l);
  STEP2(13, 1, 0, w1h, w1l, w0h, w0l);
  WAITV(3); __builtin_amdgcn_s_barrier();
  CK2(2, w2h, w2l);
  WAITV(0); __builtin_amdgcn_s_barrier();
  CK2(0, w0h, w0l);
#undef STEP2

  // epilogue: bias + fast tanh, row-major f32 out (compiler vmem after drain)
  const float bv = bias[n0col + lr];
  #pragma unroll
  for (int fr = 0; fr < 2; ++fr)
    #pragma unroll
    for (int r = 0; r < 4; ++r) {
      const int row = mx * 32 + fr * 16 + kg * 4 + r;
      out[(size_t)row * FEATC + n0col + lr] = tanh_fast(acc[fr][r] + bv);
    }
}

}  // namespace

extern "C" void kernel_launch(void* const* d_in, const int* in_sizes, int n_in,
                              void* d_out, int out_size, void* d_ws, size_t ws_size,
                              hipStream_t stream) {
  const float* x     = (const float*)d_in[0];
  const float* nodes = (const float*)d_in[1];
  // d_in[2] = edge_weight: forward value ew/ew == 1.0 -> unused.
  const float* W1s = (const float*)d_in[3];
  const float* W1n = (const float*)d_in[4];
  const float* b1  = (const float*)d_in[5];
  const float* W2s = (const float*)d_in[6];
  const float* W2n = (const float*)d_in[7];
  const float* b2  = (const float*)d_in[8];
  float* out = (float*)d_out;

  // workspace (ushort): A1F + A2F + WF1 + WF2 = 36.7 MB
  const size_t a1_sz = (size_t)BQ * M1 * 1024;      // 9,437,184
  const size_t a2_sz = (size_t)BQ * M2 * 1024;      // 8,388,608
  const size_t wf_sz = (size_t)16 * 16 * 2 * 512;   // 262,144 per layer
  const size_t need = (a1_sz + a2_sz + 2 * wf_sz) * sizeof(ushort);
  if (ws_size < need) return;

  ushort* p = (ushort*)d_ws;
  ushort* A1F = p; p += a1_sz;
  ushort* A2F = p; p += a2_sz;
  ushort* WF1 = p; p += wf_sz;
  ushort* WF2 = p; p += wf_sz;

  prep_fused<<<640, 256, 0, stream>>>(x, nodes, W1s, W1n, W2s, W2n,
                                      A1F, WF1, WF2);
  gemm1_fused<<<dim3(BQ * 2, FEATC / 64), 256, 0, stream>>>(A1F, WF1, b1, A2F);
  gemm2_lds<<<dim3(256, 4), 256, 0, stream>>>(A2F, WF2, b2, out);
}

// Round 20
// 37.205 us; speedup vs baseline: 4.5100x; 1.0151x over previous
//
#include <hip/hip_runtime.h>
#include <hip/hip_bf16.h>

// SparseGCM: 2-layer causal-window GCN on MI355X — split-bf16, fragment-
// contiguous layout, LINEARITY restructure (R20):
//   winsum(n)@Wn == winsum(n@Wn)  ->  K=256 GEMMs (8 steps, half staging),
//   window sums done on GEMM OUTPUTS in fp32 epilogues; prep is a pure
//   streaming split/transpose (no serial window chain, no win segments).
// Chain: prep_all -> gemm1_lin (U=n@W1s, V=n@W1n, winsum epi -> h1 frag)
//        -> gemm2_lin (P=h1@W2s, Q=h1@W2n, winsum epi -> d_out).
//
// Precision (R2/R4): single-bf16 fails (correlated L1 errors x16-amplified).
// Split v = hi+lo bf16; Ahi*Whi + Ahi*Wlo + Alo*Whi (3 MFMAs) ~= fp32.
// Winsum moved across the linear op: numerically equivalent (f32 sum of 16
// per-row products vs product of f32 sum) — absmax expected ~0.004.
//
// Perf history: R5 61.2; R7 55.8; R8 49.7; R9 ABORT (compiler vmem inside
// asm region); R10 47.8; R11 45.5; R12 41.2; R14 37.4; R15 35.8 (best);
// R16/R17 neutral (depth/barriers not the limiter); R18 167.8 (grid.sync
// disaster); R19 37.8 (4 blk/CU regression). R20 attacks data volume + step
// count, the only levers left.

namespace {

constexpr int BQ    = 64;
constexpr int FEATC = 256;

using ushort = unsigned short;
using short8 = __attribute__((ext_vector_type(8))) short;   // 8 bf16
using f32x4  = __attribute__((ext_vector_type(4))) float;

__device__ __forceinline__ ushort f2bf(float f) {  // RNE
  union { float f; unsigned u; } v{f};
  unsigned r = v.u + 0x7FFFu + ((v.u >> 16) & 1u);
  return (ushort)(r >> 16);
}
__device__ __forceinline__ float bf2f(ushort h) {
  union { unsigned u; float f; } v{(unsigned)h << 16};
  return v.f;
}
__device__ __forceinline__ void split2(float v, ushort& hi, ushort& lo) {
  hi = f2bf(v);
  lo = f2bf(v - bf2f(hi));
}
__device__ __forceinline__ float tanh_fast(float x) {
  const float e = __builtin_amdgcn_exp2f(x * 2.8853900817779268f);
  return 1.0f - 2.0f * __builtin_amdgcn_rcpf(1.0f + e);
}
__device__ __forceinline__ void gl_lds16(const ushort* g, ushort* l) {
  __builtin_amdgcn_global_load_lds(
      (const __attribute__((address_space(1))) void*)g,
      (__attribute__((address_space(3))) void*)l, 16, 0, 0);
}

// K=256 fragment layout. Buffer = array of 1KB units; unit (rowgrp, kb, s):
// idx = ((rg*8 + kb)*2 + s)*512; within: ((k>>3)&3)*128 + (row&15)*8 + (k&7).
__device__ __forceinline__ int lofs(int row_l, int k, int s) {  // LDS-local
  return ((k >> 5) * 2 + s) * 512 + ((k >> 3) & 3) * 128 + row_l * 8 + (k & 7);
}
__device__ __forceinline__ size_t wfrag(int n, int k, int s) {  // weights
  return ((size_t)(((n >> 4) * 8 + (k >> 5)) * 2 + s)) * 512
       + ((k >> 3) & 3) * 128 + (n & 15) * 8 + (k & 7);
}

// ---------------------------------------------------------------------------
// prep_all: blocks [0,640) = node rows -> NF frag buffer (b = blk/10,
// rg = blk%10 covers nodes 480+16rg..+16); blocks [640,704) = weight
// transpose+split -> WS1/WN1/WS2/WN2 frag buffers.
// ---------------------------------------------------------------------------
__global__ __launch_bounds__(256) void prep_all(
    const float* __restrict__ x, const float* __restrict__ nodes,
    const float* __restrict__ W1s, const float* __restrict__ W1n,
    const float* __restrict__ W2s, const float* __restrict__ W2n,
    ushort* __restrict__ NF, ushort* __restrict__ WS1,
    ushort* __restrict__ WN1, ushort* __restrict__ WS2,
    ushort* __restrict__ WN2) {
  __shared__ __align__(16) ushort lds_o[8192];   // one rg frag group (16KB)
  __shared__ float tile[64][65];
  const int blk = blockIdx.x, tid = threadIdx.x;
  if (blk < 640) {
    const int b = blk / 10, rg = blk % 10, f = tid;
    const float* nb = nodes + ((size_t)b * 640) * FEATC + f;
    const float* xb = x     + ((size_t)b * 128) * FEATC + f;
    #pragma unroll
    for (int tt = 0; tt < 16; ++tt) {
      const int i = 480 + rg * 16 + tt;
      const float v = (i < 512) ? nb[(size_t)i * FEATC]
                                : xb[(size_t)(i - 512) * FEATC];
      ushort hi, lo;
      split2(v, hi, lo);
      lds_o[lofs(tt, f, 0)] = hi;
      lds_o[lofs(tt, f, 1)] = lo;
    }
    __syncthreads();
    ushort* dst = NF + (size_t)(b * 10 + rg) * 8192;
    #pragma unroll
    for (int it = 0; it < 4; ++it) {
      const int idx = it * 256 + tid;
      *(short8*)(dst + idx * 8) = *(const short8*)(lds_o + idx * 8);
    }
  } else {
    const int w = blk - 640;
    const int z = w >> 4, rem = w & 15;
    const int k0 = (rem >> 2) * 64, n0 = (rem & 3) * 64;
    const float* src = (z == 0) ? W1s : (z == 1) ? W1n : (z == 2) ? W2s : W2n;
    ushort* dst = (z == 0) ? WS1 : (z == 1) ? WN1 : (z == 2) ? WS2 : WN2;
    const int c = tid & 63, r4 = tid >> 6;
    #pragma unroll
    for (int p = 0; p < 16; ++p) {
      const int k = r4 + p * 4;
      tile[k][c] = src[(size_t)(k0 + k) * FEATC + n0 + c];
    }
    __syncthreads();
    #pragma unroll
    for (int p = 0; p < 16; ++p) {
      const int n = r4 + p * 4;
      ushort hi, lo;
      split2(tile[c][n], hi, lo);
      dst[wfrag(n0 + n, k0 + c, 0)] = hi;
      dst[wfrag(n0 + n, k0 + c, 1)] = lo;
    }
  }
}

// ---------------------------------------------------------------------------
// asm helpers (R9 rule: only asm vmem / gl_lds inside the pipelined window).
// ---------------------------------------------------------------------------
#define GLOAD(dst, ptr)                                                      \
  asm volatile("global_load_dwordx4 %0, %1, off"                             \
               : "=v"(dst) : "v"(ptr) : "memory")

#define WAITV(n) do {                                                        \
  asm volatile("s_waitcnt vmcnt(" #n ")" ::: "memory");                      \
  __builtin_amdgcn_sched_barrier(0);                                         \
} while (0)

#define MF(a, b, c) c = __builtin_amdgcn_mfma_f32_16x16x32_bf16(a, b, c, 0, 0, 0)

struct W4 { short8 sh, sl, nh, nl; };
#define LW(S, bWS, bWN, kb) do {                                             \
  GLOAD(S.sh, bWS + (kb) * 1024); GLOAD(S.sl, bWS + (kb) * 1024 + 512);      \
  GLOAD(S.nh, bWN + (kb) * 1024); GLOAD(S.nl, bWN + (kb) * 1024 + 512);      \
} while (0)

// ---------------------------------------------------------------------------
// gemm1_lin: grid (192,4), 3 blocks/CU. Block (mx=3b+sub, ny): output h1
// nodes [496+48sub .. +48), input n nodes [480+48sub .. +64) = 4 row-groups.
// Per step: 8 A units staged (2/wave, uniform), 4 W loads/wave -> cohort 6,
// depth-2, steady vmcnt(6). Q = n@W1n (4 frags), P = n@W1s (frags 1..3).
// Epilogue: winsum(Q) + P + bias -> tanh -> split -> H1F frag units.
// ---------------------------------------------------------------------------
#define STG1(jn, kb) do {                                                    \
  gl_lds16(srcA0 + (kb) * 1024, sb1 + (jn) * 4096 + u0 * 512);               \
  gl_lds16(srcA1 + (kb) * 1024, sb1 + (jn) * 4096 + u1 * 512);               \
} while (0)

#define COMP1(j, Wt) do {                                                    \
  const ushort* bp_ = sb1 + (j) * 4096 + lane * 8;                           \
  const short8 a0h = *(const short8*)(bp_ + 0 * 512);                        \
  const short8 a0l = *(const short8*)(bp_ + 1 * 512);                        \
  const short8 a1h = *(const short8*)(bp_ + 2 * 512);                        \
  const short8 a1l = *(const short8*)(bp_ + 3 * 512);                        \
  const short8 a2h = *(const short8*)(bp_ + 4 * 512);                        \
  const short8 a2l = *(const short8*)(bp_ + 5 * 512);                        \
  const short8 a3h = *(const short8*)(bp_ + 6 * 512);                        \
  const short8 a3l = *(const short8*)(bp_ + 7 * 512);                        \
  __builtin_amdgcn_s_setprio(1);                                            \
  MF(a0h, Wt.nh, Q[0]); MF(a1h, Wt.nh, Q[1]);                                \
  MF(a2h, Wt.nh, Q[2]); MF(a3h, Wt.nh, Q[3]);                                \
  MF(a0h, Wt.nl, Q[0]); MF(a1h, Wt.nl, Q[1]);                                \
  MF(a2h, Wt.nl, Q[2]); MF(a3h, Wt.nl, Q[3]);                                \
  MF(a0l, Wt.nh, Q[0]); MF(a1l, Wt.nh, Q[1]);                                \
  MF(a2l, Wt.nh, Q[2]); MF(a3l, Wt.nh, Q[3]);                                \
  MF(a1h, Wt.sh, P[0]); MF(a2h, Wt.sh, P[1]); MF(a3h, Wt.sh, P[2]);          \
  MF(a1h, Wt.sl, P[0]); MF(a2h, Wt.sl, P[1]); MF(a3h, Wt.sl, P[2]);          \
  MF(a1l, Wt.sh, P[0]); MF(a2l, Wt.sh, P[1]); MF(a3l, Wt.sh, P[2]);          \
  __builtin_amdgcn_s_setprio(0);                                            \
  __builtin_amdgcn_sched_barrier(0);                                        \
} while (0)

__global__ __launch_bounds__(256, 3) void gemm1_lin(
    const ushort* __restrict__ NF, const ushort* __restrict__ WS,
    const ushort* __restrict__ WN, const float* __restrict__ bias,
    ushort* __restrict__ H1F) {
  // LDS: stage 3 x 8KB at 0; epilogue: Qt[64][68] f32 at 0 (17408),
  // Pt[48][68] at 17408 (13056), outb 12KB at 30464. Total 42752.
  __shared__ __align__(16) unsigned char ldsmem[42752];
  ushort* sb1 = (ushort*)ldsmem;
  float (*Qt)[68] = (float(*)[68])ldsmem;
  float (*Pt)[68] = (float(*)[68])(ldsmem + 17408);
  ushort* outb = (ushort*)(ldsmem + 30464);

  const int tid = threadIdx.x;
  const int wave = tid >> 6, lane = tid & 63;
  const int lr = lane & 15, kg = lane >> 4;
  const int mx = blockIdx.x, ny = blockIdx.y;
  const int b = mx / 3, sub = mx % 3;
  const int rgN0 = 3 * sub;                   // first of 4 n row-groups
  const int ngw = ny * 4 + wave;

  const int u0 = wave * 2, u1 = wave * 2 + 1;
  const ushort* srcA0 =
      NF + ((size_t)((b * 10 + rgN0 + (u0 >> 1)) * 16) + (u0 & 1)) * 512 + lane * 8;
  const ushort* srcA1 =
      NF + ((size_t)((b * 10 + rgN0 + (u1 >> 1)) * 16) + (u1 & 1)) * 512 + lane * 8;
  const ushort* bWS = WS + (size_t)ngw * 8192 + lane * 8;
  const ushort* bWN = WN + (size_t)ngw * 8192 + lane * 8;

  f32x4 Q[4] = {}, P[3] = {};
  W4 w0, w1, w2;

  STG1(0, 0); LW(w0, bWS, bWN, 0);
  STG1(1, 1); LW(w1, bWS, bWN, 1);

  WAITV(6); __builtin_amdgcn_s_barrier(); COMP1(0, w0);
  STG1(2, 2); LW(w2, bWS, bWN, 2);
  WAITV(6); __builtin_amdgcn_s_barrier(); COMP1(1, w1);
  STG1(0, 3); LW(w0, bWS, bWN, 3);
  WAITV(6); __builtin_amdgcn_s_barrier(); COMP1(2, w2);
  STG1(1, 4); LW(w1, bWS, bWN, 4);
  WAITV(6); __builtin_amdgcn_s_barrier(); COMP1(0, w0);
  STG1(2, 5); LW(w2, bWS, bWN, 5);
  WAITV(6); __builtin_amdgcn_s_barrier(); COMP1(1, w1);
  STG1(0, 6); LW(w0, bWS, bWN, 6);
  WAITV(6); __builtin_amdgcn_s_barrier(); COMP1(2, w2);
  STG1(1, 7); LW(w1, bWS, bWN, 7);
  WAITV(6); __builtin_amdgcn_s_barrier(); COMP1(0, w0);
  WAITV(0); __builtin_amdgcn_s_barrier(); COMP1(1, w1);

  __syncthreads();   // all waves done with stage LDS -> reuse as Qt/Pt

  // dump accumulators
  #pragma unroll
  for (int fr = 0; fr < 4; ++fr)
    #pragma unroll
    for (int r = 0; r < 4; ++r)
      Qt[fr * 16 + kg * 4 + r][wave * 16 + lr] = Q[fr][r];
  #pragma unroll
  for (int p = 0; p < 3; ++p)
    #pragma unroll
    for (int r = 0; r < 4; ++r)
      Pt[p * 16 + kg * 4 + r][wave * 16 + lr] = P[p][r];
  __syncthreads();

  // winsum epilogue: thread (q = tid>>6, col = tid&63) handles t in
  // [q*12, q*12+12). h1 = tanh(P[t] + sum Qt[t..t+16) + bias).
  {
    const int col = tid & 63, q = tid >> 6;
    const float bv = bias[ny * 64 + col];
    const int t0 = q * 12;
    float win = 0.f;
    #pragma unroll
    for (int d = 0; d < 16; ++d) win += Qt[t0 + d][col];
    for (int tt = 0; tt < 12; ++tt) {
      const int t = t0 + tt;
      const float h = tanh_fast(Pt[t][col] + win + bv);
      ushort hi, lo;
      split2(h, hi, lo);
      const int base = (((t >> 4) * 2 + (col >> 5)) * 2) * 512
                     + ((col >> 3) & 3) * 128 + (t & 15) * 8 + (col & 7);
      outb[base]       = hi;
      outb[base + 512] = lo;
      if (tt < 11) win += Qt[t + 16][col] - Qt[t][col];
    }
  }
  __syncthreads();

  // burst 12 units of 1KB to H1F
  #pragma unroll
  for (int it = 0; it < 3; ++it) {
    const int lin = it * 2048 + tid * 8;
    const int u = lin >> 9, w = lin & 511;
    const int lrg = u >> 2, lkb = (u >> 1) & 1, s = u & 1;
    const size_t dst =
        ((size_t)((b * 9 + 3 * sub + lrg) * 8 + ny * 2 + lkb) * 2 + s) * 512 + w;
    *(short8*)(H1F + dst) = *(const short8*)(outb + lin);
  }
}

// ---------------------------------------------------------------------------
// gemm2_lin: grid (128,4), 2 blocks/CU. Block (mx=2b+h, ny): output nodes
// [512+64h .. +64), input h1 local rows [64h .. +80) = 5 row-groups.
// Per step: 10 A units (waves 0,1: 3; waves 2,3: 2) + 4 W -> cohort 7/6,
// depth-2, vmcnt(7)/(6). Q = h1@W2n (5 frags), P = h1@W2s (frags 1..4).
// Epilogue: winsum(Q) + P + bias -> tanh -> f32 d_out (coalesced).
// ---------------------------------------------------------------------------
#define STG2(jn, kb) do {                                                    \
  gl_lds16(srcB0 + (kb) * 1024, sb2 + (jn) * 5120 + v0 * 512);               \
  gl_lds16(srcB1 + (kb) * 1024, sb2 + (jn) * 5120 + v1 * 512);               \
  if (g3) gl_lds16(srcB2 + (kb) * 1024, sb2 + (jn) * 5120 + v2 * 512);       \
} while (0)

#define WAITW do { if (g3) { WAITV(7); } else { WAITV(6); } } while (0)

#define COMP2(j, Wt) do {                                                    \
  const ushort* bp_ = sb2 + (j) * 5120 + lane * 8;                           \
  const short8 a0h = *(const short8*)(bp_ + 0 * 512);                        \
  const short8 a0l = *(const short8*)(bp_ + 1 * 512);                        \
  const short8 a1h = *(const short8*)(bp_ + 2 * 512);                        \
  const short8 a1l = *(const short8*)(bp_ + 3 * 512);                        \
  const short8 a2h = *(const short8*)(bp_ + 4 * 512);                        \
  const short8 a2l = *(const short8*)(bp_ + 5 * 512);                        \
  const short8 a3h = *(const short8*)(bp_ + 6 * 512);                        \
  const short8 a3l = *(const short8*)(bp_ + 7 * 512);                        \
  const short8 a4h = *(const short8*)(bp_ + 8 * 512);                        \
  const short8 a4l = *(const short8*)(bp_ + 9 * 512);                        \
  __builtin_amdgcn_s_setprio(1);                                            \
  MF(a0h, Wt.nh, Q[0]); MF(a1h, Wt.nh, Q[1]); MF(a2h, Wt.nh, Q[2]);          \
  MF(a3h, Wt.nh, Q[3]); MF(a4h, Wt.nh, Q[4]);                                \
  MF(a0h, Wt.nl, Q[0]); MF(a1h, Wt.nl, Q[1]); MF(a2h, Wt.nl, Q[2]);          \
  MF(a3h, Wt.nl, Q[3]); MF(a4h, Wt.nl, Q[4]);                                \
  MF(a0l, Wt.nh, Q[0]); MF(a1l, Wt.nh, Q[1]); MF(a2l, Wt.nh, Q[2]);          \
  MF(a3l, Wt.nh, Q[3]); MF(a4l, Wt.nh, Q[4]);                                \
  MF(a1h, Wt.sh, P[0]); MF(a2h, Wt.sh, P[1]);                                \
  MF(a3h, Wt.sh, P[2]); MF(a4h, Wt.sh, P[3]);                                \
  MF(a1h, Wt.sl, P[0]); MF(a2h, Wt.sl, P[1]);                                \
  MF(a3h, Wt.sl, P[2]); MF(a4h, Wt.sl, P[3]);                                \
  MF(a1l, Wt.sh, P[0]); MF(a2l, Wt.sh, P[1]);                                \
  MF(a3l, Wt.sh, P[2]); MF(a4l, Wt.sh, P[3]);                                \
  __builtin_amdgcn_s_setprio(0);                                            \
  __builtin_amdgcn_sched_barrier(0);                                        \
} while (0)

__global__ __launch_bounds__(256, 2) void gemm2_lin(
    const ushort* __restrict__ H1F, const ushort* __restrict__ WS,
    const ushort* __restrict__ WN, const float* __restrict__ bias,
    float* __restrict__ out) {
  // LDS: stage 3 x 10KB at 0; epilogue Qt[80][68] at 0 (21760),
  // Pt[64][68] at 21760 (17408). Total 39168.
  __shared__ __align__(16) unsigned char ldsmem[39168];
  ushort* sb2 = (ushort*)ldsmem;
  float (*Qt)[68] = (float(*)[68])ldsmem;
  float (*Pt)[68] = (float(*)[68])(ldsmem + 21760);

  const int tid = threadIdx.x;
  const int wave = tid >> 6, lane = tid & 63;
  const int lr = lane & 15, kg = lane >> 4;
  const int mx = blockIdx.x, ny = blockIdx.y;
  const int b = mx >> 1, h = mx & 1;
  const int rgH0 = 4 * h;                     // first of 5 h1 row-groups
  const int ngw = ny * 4 + wave;

  const bool g3 = (wave < 2);
  const int vw = g3 ? wave * 3 : 6 + (wave - 2) * 2;
  const int v0 = vw, v1 = vw + 1, v2 = g3 ? vw + 2 : vw + 1;
  auto srcH = [&](int u) {
    return H1F + ((size_t)((b * 9 + rgH0 + (u >> 1)) * 16) + (u & 1)) * 512
           + lane * 8;
  };
  const ushort* srcB0 = srcH(v0);
  const ushort* srcB1 = srcH(v1);
  const ushort* srcB2 = srcH(v2);
  const ushort* bWS = WS + (size_t)ngw * 8192 + lane * 8;
  const ushort* bWN = WN + (size_t)ngw * 8192 + lane * 8;

  f32x4 Q[5] = {}, P[4] = {};
  W4 w0, w1, w2;

  STG2(0, 0); LW(w0, bWS, bWN, 0);
  STG2(1, 1); LW(w1, bWS, bWN, 1);

  WAITW; __builtin_amdgcn_s_barrier(); COMP2(0, w0);
  STG2(2, 2); LW(w2, bWS, bWN, 2);
  WAITW; __builtin_amdgcn_s_barrier(); COMP2(1, w1);
  STG2(0, 3); LW(w0, bWS, bWN, 3);
  WAITW; __builtin_amdgcn_s_barrier(); COMP2(2, w2);
  STG2(1, 4); LW(w1, bWS, bWN, 4);
  WAITW; __builtin_amdgcn_s_barrier(); COMP2(0, w0);
  STG2(2, 5); LW(w2, bWS, bWN, 5);
  WAITW; __builtin_amdgcn_s_barrier(); COMP2(1, w1);
  STG2(0, 6); LW(w0, bWS, bWN, 6);
  WAITW; __builtin_amdgcn_s_barrier(); COMP2(2, w2);
  STG2(1, 7); LW(w1, bWS, bWN, 7);
  WAITW; __builtin_amdgcn_s_barrier(); COMP2(0, w0);
  WAITV(0); __builtin_amdgcn_s_barrier(); COMP2(1, w1);

  __syncthreads();   // stage LDS -> Qt/Pt reuse

  #pragma unroll
  for (int fr = 0; fr < 5; ++fr)
    #pragma unroll
    for (int r = 0; r < 4; ++r)
      Qt[fr * 16 + kg * 4 + r][wave * 16 + lr] = Q[fr][r];
  #pragma unroll
  for (int p = 0; p < 4; ++p)
    #pragma unroll
    for (int r = 0; r < 4; ++r)
      Pt[p * 16 + kg * 4 + r][wave * 16 + lr] = P[p][r];
  __syncthreads();

  // winsum epilogue: thread (q, col) handles t in [q*16, q*16+16);
  // out = tanh(P[t] + sum Qt[t..t+16) + bias), stored in-place into Pt.
  {
    const int col = tid & 63, q = tid >> 6;
    const float bv = bias[ny * 64 + col];
    const int t0 = q * 16;
    float win = 0.f;
    #pragma unroll
    for (int d = 0; d < 16; ++d) win += Qt[t0 + d][col];
    for (int tt = 0; tt < 16; ++tt) {
      const int t = t0 + tt;
      const float o = tanh_fast(Pt[t][col] + win + bv);
      if (tt < 15) win += Qt[t + 16][col] - Qt[t][col];
      Pt[t][col] = o;
    }
  }
  __syncthreads();

  // coalesced f32 out: rows b*128 + 64h + trow, cols ny*64 + ch*4
  #pragma unroll
  for (int it = 0; it < 4; ++it) {
    const int idx = it * 256 + tid;
    const int trow = idx >> 4, ch = idx & 15;
    *(f32x4*)(out + (size_t)(b * 128 + 64 * h + trow) * FEATC + ny * 64 + ch * 4) =
        *(const f32x4*)&Pt[trow][ch * 4];
  }
}

}  // namespace

extern "C" void kernel_launch(void* const* d_in, const int* in_sizes, int n_in,
                              void* d_out, int out_size, void* d_ws, size_t ws_size,
                              hipStream_t stream) {
  const float* x     = (const float*)d_in[0];
  const float* nodes = (const float*)d_in[1];
  // d_in[2] = edge_weight: forward value ew/ew == 1.0 -> unused.
  const float* W1s = (const float*)d_in[3];
  const float* W1n = (const float*)d_in[4];
  const float* b1  = (const float*)d_in[5];
  const float* W2s = (const float*)d_in[6];
  const float* W2n = (const float*)d_in[7];
  const float* b2  = (const float*)d_in[8];
  float* out = (float*)d_out;

  // workspace (ushort elems): NF 5,242,880 + H1F 4,718,592 + 4x W 131,072
  // = 10,485,760 elems = 20.97 MB (< previous 36.7 MB, fits)
  const size_t nf_sz = (size_t)BQ * 10 * 8192;
  const size_t h1_sz = (size_t)BQ * 9 * 8192;
  const size_t w_sz  = (size_t)16 * 8 * 2 * 512;
  const size_t need = (nf_sz + h1_sz + 4 * w_sz) * sizeof(ushort);
  if (ws_size < need) return;

  ushort* p = (ushort*)d_ws;
  ushort* NF  = p; p += nf_sz;
  ushort* H1F = p; p += h1_sz;
  ushort* WS1 = p; p += w_sz;
  ushort* WN1 = p; p += w_sz;
  ushort* WS2 = p; p += w_sz;
  ushort* WN2 = p; p += w_sz;

  prep_all<<<704, 256, 0, stream>>>(x, nodes, W1s, W1n, W2s, W2n,
                                    NF, WS1, WN1, WS2, WN2);
  gemm1_lin<<<dim3(192, 4), 256, 0, stream>>>(NF, WS1, WN1, b1, H1F);
  gemm2_lin<<<dim3(128, 4), 256, 0, stream>>>(H1F, WS2, WN2, b2, out);
}

// Round 21
// 35.702 us; speedup vs baseline: 4.6999x; 1.0421x over previous
//
#include <hip/hip_runtime.h>
#include <hip/hip_bf16.h>

// SparseGCM: 2-layer causal-window GCN on MI355X — split-bf16, fragment-
// contiguous layout, 3-kernel chain, BOTH gemms with LDS-shared A:
//   prep_fused -> gemm1_fused (LDS-A + halo winsum epilogue) -> gemm2_lds.
// FINAL (R21): byte-for-byte revert to R15, the empirical optimum.
//
// Edges are j->i for j in [i-16,i) per batch, weights normalize to 1.0 ->
// "gather+segment_sum" == 16-wide sliding-window sum. Only outputs i in
// [512,640) matter: layer1 computes i in [496,640).
//
// Precision (R2/R4): single-bf16 fails (correlated L1 errors x16-amplified by
// the L2 window sum). Split v = hi+lo bf16; compute Ahi*Whi + Ahi*Wlo +
// Alo*Whi (3 MFMAs) ~= fp32. Validated R5-R20 (absmax 0.0039).
//
// Perf history: R1 107.3 (fp32 VALU); R5 61.2; R7 55.8; R8 49.7; R9 ABORT
// (compiler vmem inside asm-vmcnt region); R10 47.8; R11 45.5; R12 41.2;
// R13 41.7 (phase-lock neutral); R14 37.4 (gemm1 LDS-A); R15 35.8 (BEST);
// R16 35.9 / R17 36.1 (depth/barrier neutral); R18 167.8 (grid.sync
// disaster); R19 37.8 (4 blk/CU regression); R20 37.2 (K=256 linearity
// restructure: correct but not faster -> steps/staging are NOT the limiter).
// Conclusion: plateau at ~35.8 is the practical floor for this 3-phase
// structure; all step/stage/barrier/occupancy/launch levers are exhausted.

namespace {

constexpr int BQ    = 64;
constexpr int FEATC = 256;
constexpr int M1 = 144;   // layer-1 rows/batch: i in [496,640)
constexpr int M2 = 128;   // layer-2 rows/batch: i in [512,640)

using ushort = unsigned short;
using short8 = __attribute__((ext_vector_type(8))) short;   // 8 bf16
using f32x4  = __attribute__((ext_vector_type(4))) float;

__device__ __forceinline__ ushort f2bf(float f) {  // RNE
  union { float f; unsigned u; } v{f};
  unsigned r = v.u + 0x7FFFu + ((v.u >> 16) & 1u);
  return (ushort)(r >> 16);
}
__device__ __forceinline__ float bf2f(ushort h) {
  union { unsigned u; float f; } v{(unsigned)h << 16};
  return v.f;
}
__device__ __forceinline__ void split2(float v, ushort& hi, ushort& lo) {
  hi = f2bf(v);
  lo = f2bf(v - bf2f(hi));
}
// tanh(x) = 1 - 2/(1 + exp2(2*log2e*x)); exp2/rcp handle the limits.
__device__ __forceinline__ float tanh_fast(float x) {
  const float e = __builtin_amdgcn_exp2f(x * 2.8853900817779268f);
  return 1.0f - 2.0f * __builtin_amdgcn_rcpf(1.0f + e);
}
__device__ __forceinline__ void gl_lds16(const ushort* g, ushort* l) {
  __builtin_amdgcn_global_load_lds(
      (const __attribute__((address_space(1))) void*)g,
      (__attribute__((address_space(3))) void*)l, 16, 0, 0);
}

// Fragment-contiguous layout. Row r, packed k in [0,512) ([self|win] for A,
// [Wself|Wnbr] for W), s = hi(0)/lo(1) (for W: W1/W2). A wave's MFMA fragment
// = contiguous 1KB block at ((rg*16 + kb)*2 + s)*512, lane-linear inside.
__device__ __forceinline__ size_t frag_idx(int row, int k, int s) {
  return ((size_t)(((row >> 4) * 16 + (k >> 5)) * 2 + s)) * 512
       + ((k >> 3) & 3) * 128 + (row & 15) * 8 + (k & 7);
}
// Same, local to one 16-row group (16384-elem block).
__device__ __forceinline__ int lofs(int row_l, int k, int s) {
  return ((k >> 5) * 2 + s) * 512 + ((k >> 3) & 3) * 128 + row_l * 8 + (k & 7);
}

// ---------------------------------------------------------------------------
// prep_fused: blocks [0,576) = prep1 (A1F via LDS burst, XCD-permuted);
//             blocks [576,640) = weight transpose+split.
// ---------------------------------------------------------------------------
__global__ __launch_bounds__(256) void prep_fused(
    const float* __restrict__ x, const float* __restrict__ nodes,
    const float* __restrict__ W1s, const float* __restrict__ W1n,
    const float* __restrict__ W2s, const float* __restrict__ W2n,
    ushort* __restrict__ A1F, ushort* __restrict__ WF1,
    ushort* __restrict__ WF2) {
  __shared__ ushort lds_o[16384];   // one 16-row frag group (32 KB)
  __shared__ float tile[64][65];
  const int blk = blockIdx.x;
  if (blk < 576) {
    const int G = 4 * (blk % 144) + (blk / 144);   // XCD spread permutation
    const int b = G / 9, c = G % 9, f = threadIdx.x;
    const int t0 = c * 16, i0 = 496 + t0;
    const float* nb = nodes + ((size_t)b * 640) * FEATC + f;
    const float* xb = x     + ((size_t)b * 128) * FEATC + f;

    float v[32];
    #pragma unroll
    for (int d = 0; d < 32; ++d) {
      const int i = i0 - 16 + d;
      v[d] = (i < 512) ? nb[(size_t)i * FEATC] : xb[(size_t)(i - 512) * FEATC];
    }
    float win = 0.f;
    #pragma unroll
    for (int d = 0; d < 16; ++d) win += v[d];

    #pragma unroll
    for (int tt = 0; tt < 16; ++tt) {
      ushort hi, lo;
      split2(v[16 + tt], hi, lo);
      lds_o[lofs(tt, f, 0)] = hi;
      lds_o[lofs(tt, f, 1)] = lo;
      split2(win, hi, lo);
      lds_o[lofs(tt, 256 + f, 0)] = hi;
      lds_o[lofs(tt, 256 + f, 1)] = lo;
      win += v[16 + tt] - v[tt];
    }
    __syncthreads();
    ushort* dst = A1F + (size_t)G * 16384;
    #pragma unroll
    for (int it = 0; it < 8; ++it) {
      const int idx = it * 256 + threadIdx.x;
      *(short8*)(dst + idx * 8) = *(const short8*)(lds_o + idx * 8);
    }
  } else {
    const int w = blk - 576;
    const int z = w >> 4, rem = w & 15;
    const int k0 = (rem >> 2) * 64, n0 = (rem & 3) * 64;
    const float* src = (z == 0) ? W1s : (z == 1) ? W1n : (z == 2) ? W2s : W2n;
    ushort* dst = (z < 2) ? WF1 : WF2;
    const int koff = (z & 1) * 256;
    const int c = threadIdx.x & 63, r4 = threadIdx.x >> 6;
    #pragma unroll
    for (int p = 0; p < 16; ++p) {
      const int k = r4 + p * 4;
      tile[k][c] = src[(size_t)(k0 + k) * FEATC + n0 + c];
    }
    __syncthreads();
    #pragma unroll
    for (int p = 0; p < 16; ++p) {
      const int n = r4 + p * 4;
      ushort hi, lo;
      split2(tile[c][n], hi, lo);
      dst[frag_idx(n0 + n, koff + k0 + c, 0)] = hi;   // W1 (hi) slot
      dst[frag_idx(n0 + n, koff + k0 + c, 1)] = lo;   // W2 (lo) slot
    }
  }
}

// ---------------------------------------------------------------------------
// Shared asm helpers. Rules: only asm vmem / gl_lds builtin inside pipelined
// regions; counted vmcnt via asm; raw barrier via builtin (no drain).
// ---------------------------------------------------------------------------
#define GLOAD(dst, ptr)                                                      \
  asm volatile("global_load_dwordx4 %0, %1, off"                             \
               : "=v"(dst) : "v"(ptr) : "memory")

#define WAITV(n) do {                                                        \
  asm volatile("s_waitcnt vmcnt(" #n ")" ::: "memory");                      \
  __builtin_amdgcn_sched_barrier(0);                                         \
} while (0)

#define MF(a, b, c) c = __builtin_amdgcn_mfma_f32_16x16x32_bf16(a, b, c, 0, 0, 0)

// ---------------------------------------------------------------------------
// gemm1_fused (R14-validated): 80-row h1 window (16-row halo), A staged in
// LDS once per block, triple-buffered depth-2; W per-wave asm rotation.
// Winsum epilogue emits A2F fragment groups (LDS reused).
// ---------------------------------------------------------------------------
#define STAGEA(jn, kb) do {                                                  \
  gl_lds16(srcu0 + (kb) * 1024, sbase + (jn) * 5120 + u0 * 512);             \
  gl_lds16(srcu1 + (kb) * 1024, sbase + (jn) * 5120 + u1 * 512);             \
  if (g3) gl_lds16(srcu2 + (kb) * 1024, sbase + (jn) * 5120 + u2 * 512);     \
} while (0)

#define WAITW do { if (g3) { WAITV(5); } else { WAITV(4); } } while (0)

#define COMPJ2(j, WH, WL) do {                                               \
  const ushort* bp_ = sbase + (j) * 5120 + lane * 8;                         \
  const short8 a0h = *(const short8*)(bp_ + 0 * 512);                        \
  const short8 a0l = *(const short8*)(bp_ + 1 * 512);                        \
  const short8 a1h = *(const short8*)(bp_ + 2 * 512);                        \
  const short8 a1l = *(const short8*)(bp_ + 3 * 512);                        \
  const short8 a2h = *(const short8*)(bp_ + 4 * 512);                        \
  const short8 a2l = *(const short8*)(bp_ + 5 * 512);                        \
  const short8 a3h = *(const short8*)(bp_ + 6 * 512);                        \
  const short8 a3l = *(const short8*)(bp_ + 7 * 512);                        \
  const short8 a4h = *(const short8*)(bp_ + 8 * 512);                        \
  const short8 a4l = *(const short8*)(bp_ + 9 * 512);                        \
  __builtin_amdgcn_s_setprio(1);                                            \
  MF(a0h, WH, acc[0]); MF(a1h, WH, acc[1]); MF(a2h, WH, acc[2]);             \
  MF(a3h, WH, acc[3]); MF(a4h, WH, acc[4]);                                  \
  MF(a0h, WL, acc[0]); MF(a1h, WL, acc[1]); MF(a2h, WL, acc[2]);             \
  MF(a3h, WL, acc[3]); MF(a4h, WL, acc[4]);                                  \
  MF(a0l, WH, acc[0]); MF(a1l, WH, acc[1]); MF(a2l, WH, acc[2]);             \
  MF(a3l, WH, acc[3]); MF(a4l, WH, acc[4]);                                  \
  __builtin_amdgcn_s_setprio(0);                                            \
  __builtin_amdgcn_sched_barrier(0);                                        \
} while (0)

__global__ __launch_bounds__(256, 2) void gemm1_fused(
    const ushort* __restrict__ A, const ushort* __restrict__ W,
    const float* __restrict__ bias, ushort* __restrict__ A2F) {
  // LDS union: [0,30720) = 3 stage bufs (10KB each) during main loop;
  // epilogue reuses: hvt 80x68 f32 at 0 (21760B), outb at 21760 (32768B).
  __shared__ __align__(16) unsigned char ldsmem[54528];
  ushort* sbase = (ushort*)ldsmem;
  float (*hvt)[68] = (float(*)[68])ldsmem;
  ushort* outb = (ushort*)(ldsmem + 21760);

  const int tid = threadIdx.x;
  const int wave = tid >> 6, lane = tid & 63;
  const int lr = lane & 15, kg = lane >> 4;
  const int mx2 = blockIdx.x, ny = blockIdx.y;
  const int b = mx2 >> 1, half = mx2 & 1;
  const int rgA0 = 9 * b + 4 * half;          // first of 5 A row-groups
  const int n0 = ny * 64;
  const int ngw = ny * 4 + wave;              // W col-group for this wave

  // A staging unit assignment: unit u = g*2+s; waves 0,1 own {0..2},{3..5};
  // waves 2,3 own {6,7},{8,9}.
  const bool g3 = (wave < 2);
  const int uw = g3 ? wave * 3 : 6 + (wave - 2) * 2;
  const int u0 = uw, u1 = uw + 1, u2 = g3 ? uw + 2 : uw + 1;
  auto srcA = [&](int u) {
    return A + ((size_t)(rgA0 + (u >> 1)) * 32 + (u & 1)) * 512 + lane * 8;
  };
  const ushort* srcu0 = srcA(u0);
  const ushort* srcu1 = srcA(u1);
  const ushort* srcu2 = srcA(u2);

  const ushort* bW = W + (size_t)ngw * 16384 + lane * 8;

  f32x4 acc[5] = {};
  short8 w0h, w0l, w1h, w1l, w2h, w2l;

  // prologue: stage steps 0,1 (interleaved S,W so FIFO wait counts work)
  STAGEA(0, 0); GLOAD(w0h, bW);        GLOAD(w0l, bW + 512);
  STAGEA(1, 1); GLOAD(w1h, bW + 1024); GLOAD(w1l, bW + 1536);

#define STEP(k, j, jn, WH, WL, NWH, NWL)                                     \
  WAITW; __builtin_amdgcn_s_barrier();                                       \
  COMPJ2(j, WH, WL);                                                         \
  STAGEA(jn, (k) + 2);                                                       \
  GLOAD(NWH, bW + ((k) + 2) * 1024); GLOAD(NWL, bW + ((k) + 2) * 1024 + 512)

  STEP(0, 0, 2, w0h, w0l, w2h, w2l);
  STEP(1, 1, 0, w1h, w1l, w0h, w0l);
  STEP(2, 2, 1, w2h, w2l, w1h, w1l);
  STEP(3, 0, 2, w0h, w0l, w2h, w2l);
  STEP(4, 1, 0, w1h, w1l, w0h, w0l);
  STEP(5, 2, 1, w2h, w2l, w1h, w1l);
  STEP(6, 0, 2, w0h, w0l, w2h, w2l);
  STEP(7, 1, 0, w1h, w1l, w0h, w0l);
  STEP(8, 2, 1, w2h, w2l, w1h, w1l);
  STEP(9, 0, 2, w0h, w0l, w2h, w2l);
  STEP(10, 1, 0, w1h, w1l, w0h, w0l);
  STEP(11, 2, 1, w2h, w2l, w1h, w1l);
  STEP(12, 0, 2, w0h, w0l, w2h, w2l);
  STEP(13, 1, 0, w1h, w1l, w0h, w0l);
  WAITW; __builtin_amdgcn_s_barrier();
  COMPJ2(2, w2h, w2l);
  WAITV(0); __builtin_amdgcn_s_barrier();
  COMPJ2(0, w0h, w0l);
#undef STEP

  __syncthreads();   // LDS reuse boundary (stage bufs -> hvt/outb)

  // ---- epilogue 1: tanh -> LDS f32 tile [80 rows][64 cols] ----
  const float bv = bias[n0 + wave * 16 + lr];
  #pragma unroll
  for (int fr = 0; fr < 5; ++fr)
    #pragma unroll
    for (int r = 0; r < 4; ++r)
      hvt[fr * 16 + kg * 4 + r][wave * 16 + lr] = tanh_fast(acc[fr][r] + bv);
  __syncthreads();

  // ---- epilogue 2: per-column 16-window sums + split -> outb units ----
  {
    const int col = tid & 63, q = tid >> 6;
    float hv[32];
    #pragma unroll
    for (int d = 0; d < 32; ++d) hv[d] = hvt[q * 16 + d][col];
    float win = 0.f;
    #pragma unroll
    for (int d = 0; d < 16; ++d) win += hv[d];

    const int su = ((q * 4 + (col >> 5)) * 2) * 512
                 + ((col >> 3) & 3) * 128 + (col & 7);
    const int wu = ((q * 4 + 2 + (col >> 5)) * 2) * 512
                 + ((col >> 3) & 3) * 128 + (col & 7);
    #pragma unroll
    for (int tt = 0; tt < 16; ++tt) {
      ushort hi, lo;
      split2(hv[16 + tt], hi, lo);
      outb[su + tt * 8]       = hi;
      outb[su + tt * 8 + 512] = lo;
      split2(win, hi, lo);
      outb[wu + tt * 8]       = hi;
      outb[wu + tt * 8 + 512] = lo;
      win += hv[16 + tt] - hv[tt];
    }
  }
  __syncthreads();

  // ---- epilogue 3: burst copy 32 units of 1KB to A2F ----
  const int rg20 = 4 * mx2;
  #pragma unroll
  for (int it = 0; it < 8; ++it) {
    const int lin = it * 2048 + tid * 8;
    const int u = lin >> 9, w = lin & 511;
    const int uq = u >> 3, ukbl = (u >> 1) & 3, us = u & 1;
    const int KB = (ukbl < 2) ? (2 * ny + ukbl) : (8 + 2 * ny + (ukbl - 2));
    const size_t dst = ((size_t)((rg20 + uq) * 16 + KB) * 2 + us) * 512 + w;
    *(short8*)(A2F + dst) = *(const short8*)(outb + lin);
  }
}

// ---------------------------------------------------------------------------
// gemm2_lds (R15): mirror of gemm1's LDS-A structure, no halo.
// Grid (128, 4). Wave = 16-col W strip x 64 rows (4 row-frags, 12 MFMA/step).
// A staged once/block: 8 units of 1KB per K-step, 2 units/wave (uniform).
// Triple-buffered (24KB), depth-2, vmcnt(4) steady, vmcnt(0) last step only.
// ---------------------------------------------------------------------------
#define STAGE2(jn, kb) do {                                                  \
  gl_lds16(srcv0 + (kb) * 1024, sb2 + (jn) * 4096 + v0 * 512);               \
  gl_lds16(srcv1 + (kb) * 1024, sb2 + (jn) * 4096 + v1 * 512);               \
} while (0)

#define COMPK(j, WH, WL) do {                                                \
  const ushort* bp_ = sb2 + (j) * 4096 + lane * 8;                           \
  const short8 a0h = *(const short8*)(bp_ + 0 * 512);                        \
  const short8 a0l = *(const short8*)(bp_ + 1 * 512);                        \
  const short8 a1h = *(const short8*)(bp_ + 2 * 512);                        \
  const short8 a1l = *(const short8*)(bp_ + 3 * 512);                        \
  const short8 a2h = *(const short8*)(bp_ + 4 * 512);                        \
  const short8 a2l = *(const short8*)(bp_ + 5 * 512);                        \
  const short8 a3h = *(const short8*)(bp_ + 6 * 512);                        \
  const short8 a3l = *(const short8*)(bp_ + 7 * 512);                        \
  __builtin_amdgcn_s_setprio(1);                                            \
  MF(a0h, WH, acc[0]); MF(a1h, WH, acc[1]);                                  \
  MF(a2h, WH, acc[2]); MF(a3h, WH, acc[3]);                                  \
  MF(a0h, WL, acc[0]); MF(a1h, WL, acc[1]);                                  \
  MF(a2h, WL, acc[2]); MF(a3h, WL, acc[3]);                                  \
  MF(a0l, WH, acc[0]); MF(a1l, WH, acc[1]);                                  \
  MF(a2l, WH, acc[2]); MF(a3l, WH, acc[3]);                                  \
  __builtin_amdgcn_s_setprio(0);                                            \
  __builtin_amdgcn_sched_barrier(0);                                        \
} while (0)

__global__ __launch_bounds__(256, 2) void gemm2_lds(
    const ushort* __restrict__ A, const ushort* __restrict__ W,
    const float* __restrict__ bias, float* __restrict__ out) {
  __shared__ __align__(16) ushort sb2[3 * 4096];   // 24 KB

  const int tid = threadIdx.x;
  const int wave = tid >> 6, lane = tid & 63;
  const int lr = lane & 15, kg = lane >> 4;
  const int mx = blockIdx.x, ny = blockIdx.y;
  const int rg0 = mx * 4;                     // 4 A row-groups (64 rows)
  const int ngw = ny * 4 + wave;              // W col-group for this wave
  const int n0col = ngw * 16;

  const int v0 = wave * 2, v1 = wave * 2 + 1; // A staging units
  auto srcA = [&](int u) {
    return A + ((size_t)(rg0 + (u >> 1)) * 32 + (u & 1)) * 512 + lane * 8;
  };
  const ushort* srcv0 = srcA(v0);
  const ushort* srcv1 = srcA(v1);
  const ushort* bW = W + (size_t)ngw * 16384 + lane * 8;

  f32x4 acc[4] = {};
  short8 w0h, w0l, w1h, w1l, w2h, w2l;

  STAGE2(0, 0); GLOAD(w0h, bW);        GLOAD(w0l, bW + 512);
  STAGE2(1, 1); GLOAD(w1h, bW + 1024); GLOAD(w1l, bW + 1536);

#define STEP2(k, j, jn, WH, WL, NWH, NWL)                                    \
  WAITV(4); __builtin_amdgcn_s_barrier();                                    \
  COMPK(j, WH, WL);                                                          \
  STAGE2(jn, (k) + 2);                                                       \
  GLOAD(NWH, bW + ((k) + 2) * 1024); GLOAD(NWL, bW + ((k) + 2) * 1024 + 512)

  STEP2(0, 0, 2, w0h, w0l, w2h, w2l);
  STEP2(1, 1, 0, w1h, w1l, w0h, w0l);
  STEP2(2, 2, 1, w2h, w2l, w1h, w1l);
  STEP2(3, 0, 2, w0h, w0l, w2h, w2l);
  STEP2(4, 1, 0, w1h, w1l, w0h, w0l);
  STEP2(5, 2, 1, w2h, w2l, w1h, w1l);
  STEP2(6, 0, 2, w0h, w0l, w2h, w2l);
  STEP2(7, 1, 0, w1h, w1l, w0h, w0l);
  STEP2(8, 2, 1, w2h, w2l, w1h, w1l);
  STEP2(9, 0, 2, w0h, w0l, w2h, w2l);
  STEP2(10, 1, 0, w1h, w1l, w0h, w0l);
  STEP2(11, 2, 1, w2h, w2l, w1h, w1l);
  STEP2(12, 0, 2, w0h, w0l, w2h, w2l);
  STEP2(13, 1, 0, w1h, w1l, w0h, w0l);
  WAITV(4); __builtin_amdgcn_s_barrier();
  COMPK(2, w2h, w2l);
  WAITV(0); __builtin_amdgcn_s_barrier();
  COMPK(0, w0h, w0l);
#undef STEP2

  // epilogue: bias + fast tanh, row-major f32 out (compiler vmem after drain)
  const float bv = bias[n0col + lr];
  #pragma unroll
  for (int fr = 0; fr < 4; ++fr)
    #pragma unroll
    for (int r = 0; r < 4; ++r) {
      const int row = mx * 64 + fr * 16 + kg * 4 + r;
      out[(size_t)row * FEATC + n0col + lr] = tanh_fast(acc[fr][r] + bv);
    }
}

}  // namespace

extern "C" void kernel_launch(void* const* d_in, const int* in_sizes, int n_in,
                              void* d_out, int out_size, void* d_ws, size_t ws_size,
                              hipStream_t stream) {
  const float* x     = (const float*)d_in[0];
  const float* nodes = (const float*)d_in[1];
  // d_in[2] = edge_weight: forward value ew/ew == 1.0 -> unused.
  const float* W1s = (const float*)d_in[3];
  const float* W1n = (const float*)d_in[4];
  const float* b1  = (const float*)d_in[5];
  const float* W2s = (const float*)d_in[6];
  const float* W2n = (const float*)d_in[7];
  const float* b2  = (const float*)d_in[8];
  float* out = (float*)d_out;

  // workspace (ushort): A1F + A2F + WF1 + WF2 = 36.7 MB
  const size_t a1_sz = (size_t)BQ * M1 * 1024;      // 9,437,184
  const size_t a2_sz = (size_t)BQ * M2 * 1024;      // 8,388,608
  const size_t wf_sz = (size_t)16 * 16 * 2 * 512;   // 262,144 per layer
  const size_t need = (a1_sz + a2_sz + 2 * wf_sz) * sizeof(ushort);
  if (ws_size < need) return;

  ushort* p = (ushort*)d_ws;
  ushort* A1F = p; p += a1_sz;
  ushort* A2F = p; p += a2_sz;
  ushort* WF1 = p; p += wf_sz;
  ushort* WF2 = p; p += wf_sz;

  prep_fused<<<640, 256, 0, stream>>>(x, nodes, W1s, W1n, W2s, W2n,
                                      A1F, WF1, WF2);
  gemm1_fused<<<dim3(BQ * 2, FEATC / 64), 256, 0, stream>>>(A1F, WF1, b1, A2F);
  gemm2_lds<<<dim3((BQ * M2) / 64, FEATC / 64), 256, 0, stream>>>(
      A2F, WF2, b2, out);
}